// Round 2
// baseline (10261.495 us; speedup 1.0000x reference)
//
#include <hip/hip_runtime.h>
#include <math.h>

// Problem constants
static constexpr int S_   = 512;     // hidden size
static constexpr int S4_  = 2048;    // 4*S (gates)
static constexpr int B_   = 16;      // batch
static constexpr int T_   = 256;     // tokens
static constexpr int G_   = 32;      // groups
static constexpr int GB_  = 512;     // G*B compose rows
static constexpr int V_   = 32000;   // vocab
static constexpr int NSTEPS_ = 321;  // 1 + G*(K+2)
static constexpr int NT_LSE_ = 250;  // vocab tiles of 128

__device__ __forceinline__ float sigm(float x) { return 1.0f / (1.0f + expf(-x)); }

// ---------------------------------------------------------------- gather e = emb[tokens]
__global__ __launch_bounds__(128)
void k_gather(const int* __restrict__ tokens, const float* __restrict__ emb,
              float* __restrict__ e)
{
    int row = blockIdx.x;                 // t*16 + b
    int tok = tokens[row];
    const float4* src = (const float4*)(emb + (size_t)tok * S_);
    float4*       dst = (float4*)(e + (size_t)row * S_);
    dst[threadIdx.x] = src[threadIdx.x];  // 128 float4 = 512 floats
}

// ---------------------------------------------------------------- compose z-GEMM (one step, both dirs)
// z[d][gb][n] = bih+bhh + sum_s x[gb,s]*Wih[n,s] + sum_s h[gb,s]*Whh[n,s]
__global__ __launch_bounds__(256)
void k_compose_z(const float* __restrict__ e,
                 const float* __restrict__ hF, const float* __restrict__ hB,
                 const float* __restrict__ Wih_f, const float* __restrict__ Whh_f,
                 const float* __restrict__ bih_f, const float* __restrict__ bhh_f,
                 const float* __restrict__ Wih_b, const float* __restrict__ Whh_b,
                 const float* __restrict__ bih_b, const float* __restrict__ bhh_b,
                 float* __restrict__ zbuf, int stepk)
{
    __shared__ float As[16][64];
    __shared__ float Bs[16][64];
    const int d  = blockIdx.z;
    const int Mb = blockIdx.y * 64;
    const int Nb = blockIdx.x * 64;
    const int t  = threadIdx.x;

    const float* Wih = d ? Wih_b : Wih_f;
    const float* Whh = d ? Whh_b : Whh_f;
    const float* bih = d ? bih_b : bih_f;
    const float* bhh = d ? bhh_b : bhh_f;
    const float* h   = d ? hB : hF;
    const int child  = d ? (7 - stepk) : stepk;

    // loader mapping: 64 rows x 4 k-quads
    const int ml = t & 63;
    const int ko = (t >> 6) * 4;
    const int m  = Mb + ml;
    const int g  = m >> 4, b = m & 15;
    const float* xrow = e + ((size_t)((g * 8 + child) * 16 + b)) * S_;
    const float* hrow = h + (size_t)m * S_;
    const int n  = Nb + ml;
    const float* wi = Wih + (size_t)n * S_;
    const float* wh = Whh + (size_t)n * S_;

    const int tx = t & 15, ty = t >> 4;
    float acc[4][4] = {};

    for (int kk = 0; kk < 1024; kk += 16) {
        const float* ar = (kk < 512) ? (xrow + kk + ko) : (hrow + kk - 512 + ko);
        const float* br = (kk < 512) ? (wi + kk + ko)   : (wh + kk - 512 + ko);
        float4 av = *(const float4*)ar;
        float4 bv = *(const float4*)br;
        __syncthreads();
        As[ko + 0][ml] = av.x; As[ko + 1][ml] = av.y; As[ko + 2][ml] = av.z; As[ko + 3][ml] = av.w;
        Bs[ko + 0][ml] = bv.x; Bs[ko + 1][ml] = bv.y; Bs[ko + 2][ml] = bv.z; Bs[ko + 3][ml] = bv.w;
        __syncthreads();
#pragma unroll
        for (int k = 0; k < 16; ++k) {
            float a[4], bb[4];
#pragma unroll
            for (int i = 0; i < 4; ++i) a[i]  = As[k][ty * 4 + i];
#pragma unroll
            for (int j = 0; j < 4; ++j) bb[j] = Bs[k][tx * 4 + j];
#pragma unroll
            for (int i = 0; i < 4; ++i)
#pragma unroll
                for (int j = 0; j < 4; ++j) acc[i][j] += a[i] * bb[j];
        }
    }
#pragma unroll
    for (int i = 0; i < 4; ++i) {
        int mm = Mb + ty * 4 + i;
#pragma unroll
        for (int j = 0; j < 4; ++j) {
            int nn = Nb + tx * 4 + j;
            zbuf[((size_t)(d * 512 + mm)) * S4_ + nn] = acc[i][j] + bih[nn] + bhh[nn];
        }
    }
}

// ---------------------------------------------------------------- compose gate update
__global__ __launch_bounds__(256)
void k_compose_gates(const float* __restrict__ zbuf,
                     float* __restrict__ hF, float* __restrict__ cF,
                     float* __restrict__ hB, float* __restrict__ cB)
{
    int idx = blockIdx.x * 256 + threadIdx.x;  // 2*512*512
    int d   = idx >> 18;
    int rem = idx & ((1 << 18) - 1);
    int gb  = rem >> 9;
    int u   = rem & 511;
    const float* z = zbuf + ((size_t)(d * 512 + gb)) * S4_;
    float zi = z[u], zf = z[u + 512], zg = z[u + 1024], zo = z[u + 1536];
    float* hptr = d ? hB : hF;
    float* cptr = d ? cB : cF;
    float c = cptr[gb * S_ + u];
    c = sigm(zf) * c + sigm(zi) * tanhf(zg);
    hptr[gb * S_ + u] = sigm(zo) * tanhf(c);
    cptr[gb * S_ + u] = c;
}

// ---------------------------------------------------------------- comp = tanh([hF|hB] @ Wc.T + bc)
__global__ __launch_bounds__(256)
void k_comp(const float* __restrict__ hF, const float* __restrict__ hB,
            const float* __restrict__ Wc, const float* __restrict__ bc,
            float* __restrict__ comp)
{
    __shared__ float As[16][64];
    __shared__ float Bs[16][64];
    const int Mb = blockIdx.y * 64;
    const int Nb = blockIdx.x * 64;
    const int t  = threadIdx.x;
    const int ml = t & 63;
    const int ko = (t >> 6) * 4;
    const int m  = Mb + ml;
    const float* fr = hF + (size_t)m * S_;
    const float* br_ = hB + (size_t)m * S_;
    const int n  = Nb + ml;
    const float* wr = Wc + (size_t)n * 1024;
    const int tx = t & 15, ty = t >> 4;
    float acc[4][4] = {};

    for (int kk = 0; kk < 1024; kk += 16) {
        const float* ar = (kk < 512) ? (fr + kk + ko) : (br_ + kk - 512 + ko);
        float4 av = *(const float4*)ar;
        float4 bv = *(const float4*)(wr + kk + ko);
        __syncthreads();
        As[ko + 0][ml] = av.x; As[ko + 1][ml] = av.y; As[ko + 2][ml] = av.z; As[ko + 3][ml] = av.w;
        Bs[ko + 0][ml] = bv.x; Bs[ko + 1][ml] = bv.y; Bs[ko + 2][ml] = bv.z; Bs[ko + 3][ml] = bv.w;
        __syncthreads();
#pragma unroll
        for (int k = 0; k < 16; ++k) {
            float a[4], bb[4];
#pragma unroll
            for (int i = 0; i < 4; ++i) a[i]  = As[k][ty * 4 + i];
#pragma unroll
            for (int j = 0; j < 4; ++j) bb[j] = Bs[k][tx * 4 + j];
#pragma unroll
            for (int i = 0; i < 4; ++i)
#pragma unroll
                for (int j = 0; j < 4; ++j) acc[i][j] += a[i] * bb[j];
        }
    }
#pragma unroll
    for (int i = 0; i < 4; ++i) {
        int mm = Mb + ty * 4 + i;
#pragma unroll
        for (int j = 0; j < 4; ++j) {
            int nn = Nb + tx * 4 + j;
            comp[(size_t)mm * S_ + nn] = tanhf(acc[i][j] + bc[nn]);
        }
    }
}

// ---------------------------------------------------------------- one stack-LSTM step
// 256 blocks; block owns 2 hidden units (all 4 gates, all 16 batch rows).
// h double-buffered across launches (hsrc -> hdst) to avoid intra-step races.
__global__ __launch_bounds__(256)
void k_stack_step(const float* __restrict__ e, const float* __restrict__ comp,
                  const int* __restrict__ tokens, const float* __restrict__ emb,
                  const float* __restrict__ Wih, const float* __restrict__ Whh,
                  const float* __restrict__ bih, const float* __restrict__ bhh,
                  const float* __restrict__ hsrc, float* __restrict__ hdst,
                  float* __restrict__ cst, float* __restrict__ hp, int step)
{
    __shared__ float zsh[128];
    const int t    = threadIdx.x;
    const int p    = t >> 1, half = t & 1;
    const int b    = p >> 3, rest = p & 7;
    const int ul   = rest >> 2, gate = rest & 3;
    const int unit = blockIdx.x * 2 + ul;
    const int n    = gate * 512 + unit;

    const float* row;
    if (half == 0) {
        const float* xs;
        if (step == 0) xs = emb + (size_t)tokens[0] * S_;
        else {
            int j = step - 1, g = j / 10, r = j - g * 10;
            if (r == 0)      xs = emb + (size_t)tokens[0] * S_;
            else if (r <= 8) xs = e + ((size_t)((g * 8 + r - 1) * 16 + b)) * S_;
            else             xs = comp + ((size_t)(g * 16 + b)) * S_;
        }
        row = xs;
    } else {
        row = hsrc + (size_t)b * S_;
    }
    const float* w = (half == 0 ? Wih : Whh) + (size_t)n * S_;

    const float4* r4 = (const float4*)row;
    const float4* w4 = (const float4*)w;
    float ax = 0.f, ay = 0.f, az = 0.f, aw = 0.f;
#pragma unroll 8
    for (int q = 0; q < 128; ++q) {
        float4 a = r4[q], ww = w4[q];
        ax += a.x * ww.x; ay += a.y * ww.y; az += a.z * ww.z; aw += a.w * ww.w;
    }
    float s = (ax + ay) + (az + aw);
    float o = __shfl_xor(s, 1);
    if (half == 0) zsh[p] = s + o + bih[n] + bhh[n];
    __syncthreads();

    if (t < 32) {
        int b2   = t >> 1;
        int u2   = blockIdx.x * 2 + (t & 1);
        int base = b2 * 8 + (t & 1) * 4;
        float zi = zsh[base + 0], zf = zsh[base + 1], zg = zsh[base + 2], zo = zsh[base + 3];
        float c  = cst[b2 * S_ + u2];
        c = sigm(zf) * c + sigm(zi) * tanhf(zg);
        float hh = sigm(zo) * tanhf(c);
        cst[b2 * S_ + u2]  = c;
        hdst[b2 * S_ + u2] = hh;
        if (step >= 1) {
            int j = step - 1, g = j / 10, r = j - g * 10;
            if (r <= 7) {  // state BEFORE shifting token tt
                int tt = g * 8 + r;
                hp[((size_t)(tt * 16 + b2)) * S_ + u2] = hh;
            }
        }
    }
}

// ---------------------------------------------------------------- token logit (one wave per row)
__global__ __launch_bounds__(64)
void k_tok(const int* __restrict__ tokens, const float* __restrict__ hp,
           const float* __restrict__ Wout, const float* __restrict__ bout,
           float* __restrict__ tl)
{
    int row  = blockIdx.x;
    int lane = threadIdx.x;
    int tok  = tokens[row];
    const float4* a = (const float4*)(hp + (size_t)row * S_);
    const float4* w = (const float4*)(Wout + (size_t)tok * S_);
    float s = 0.f;
    for (int q = lane; q < 128; q += 64) {
        float4 av = a[q], wv = w[q];
        s += av.x * wv.x + av.y * wv.y + av.z * wv.z + av.w * wv.w;
    }
    for (int off = 32; off; off >>= 1) s += __shfl_down(s, off);
    if (lane == 0) tl[row] = s + bout[tok];
}

// ---------------------------------------------------------------- logits GEMM + online LSE partials
// M=4096 (hp rows), N=32000 (vocab), K=512. 128x128 tile, 8x8/thread.
__global__ __launch_bounds__(256)
void k_lse(const float* __restrict__ hp, const float* __restrict__ Wout,
           const float* __restrict__ bout, float* __restrict__ pmax,
           float* __restrict__ psum)
{
    __shared__ float As[16][128];
    __shared__ float Bs[16][128];
    __shared__ float red[128][17];
    __shared__ float rmax[128];
    const int Nb = blockIdx.x * 128;   // 250 tiles
    const int Mb = blockIdx.y * 128;   // 32 tiles
    const int t  = threadIdx.x;
    const int ml = t & 127, ko = (t >> 7) * 8;
    const float* arow = hp   + (size_t)(Mb + ml) * S_;
    const float* brow = Wout + (size_t)(Nb + ml) * S_;
    const int tx = t & 15, ty = t >> 4;
    float acc[8][8] = {};

    for (int kk = 0; kk < 512; kk += 16) {
        float4 a0 = *(const float4*)(arow + kk + ko);
        float4 a1 = *(const float4*)(arow + kk + ko + 4);
        float4 b0 = *(const float4*)(brow + kk + ko);
        float4 b1 = *(const float4*)(brow + kk + ko + 4);
        __syncthreads();
        As[ko + 0][ml] = a0.x; As[ko + 1][ml] = a0.y; As[ko + 2][ml] = a0.z; As[ko + 3][ml] = a0.w;
        As[ko + 4][ml] = a1.x; As[ko + 5][ml] = a1.y; As[ko + 6][ml] = a1.z; As[ko + 7][ml] = a1.w;
        Bs[ko + 0][ml] = b0.x; Bs[ko + 1][ml] = b0.y; Bs[ko + 2][ml] = b0.z; Bs[ko + 3][ml] = b0.w;
        Bs[ko + 4][ml] = b1.x; Bs[ko + 5][ml] = b1.y; Bs[ko + 6][ml] = b1.z; Bs[ko + 7][ml] = b1.w;
        __syncthreads();
#pragma unroll
        for (int k = 0; k < 16; ++k) {
            float a[8], bb[8];
#pragma unroll
            for (int i = 0; i < 8; ++i) a[i]  = As[k][ty * 8 + i];
#pragma unroll
            for (int j = 0; j < 8; ++j) bb[j] = Bs[k][tx * 8 + j];
#pragma unroll
            for (int i = 0; i < 8; ++i)
#pragma unroll
                for (int j = 0; j < 8; ++j) acc[i][j] += a[i] * bb[j];
        }
    }

    float bv[8];
#pragma unroll
    for (int j = 0; j < 8; ++j) bv[j] = bout[Nb + tx * 8 + j];

    // phase 1: per-row tile max
#pragma unroll
    for (int i = 0; i < 8; ++i) {
        float m = -INFINITY;
#pragma unroll
        for (int j = 0; j < 8; ++j) m = fmaxf(m, acc[i][j] + bv[j]);
        red[ty * 8 + i][tx] = m;
    }
    __syncthreads();
    if (t < 128) {
        float m = red[t][0];
#pragma unroll
        for (int x = 1; x < 16; ++x) m = fmaxf(m, red[t][x]);
        rmax[t] = m;
    }
    __syncthreads();
    // phase 2: per-row sum of exp
#pragma unroll
    for (int i = 0; i < 8; ++i) {
        float m = rmax[ty * 8 + i];
        float ss = 0.f;
#pragma unroll
        for (int j = 0; j < 8; ++j) ss += expf(acc[i][j] + bv[j] - m);
        red[ty * 8 + i][tx] = ss;
    }
    __syncthreads();
    if (t < 128) {
        float ss = 0.f;
#pragma unroll
        for (int x = 0; x < 16; ++x) ss += red[t][x];
        size_t off = (size_t)(Mb + t) * NT_LSE_ + blockIdx.x;
        pmax[off] = rmax[t];
        psum[off] = ss;
    }
}

// ---------------------------------------------------------------- final reduce: loss = LSE - tok_logit
__global__ __launch_bounds__(256)
void k_final(const float* __restrict__ pmax, const float* __restrict__ psum,
             const float* __restrict__ tl, float* __restrict__ loss)
{
    int r = blockIdx.x * 256 + threadIdx.x;  // 4096 rows
    const float* pm = pmax + (size_t)r * NT_LSE_;
    const float* ps = psum + (size_t)r * NT_LSE_;
    float M = -INFINITY, Ssum = 0.f;
    for (int nt = 0; nt < NT_LSE_; ++nt) {
        float m2 = pm[nt], s2 = ps[nt];
        float nm = fmaxf(M, m2);
        Ssum = Ssum * expf(M - nm) + s2 * expf(m2 - nm);
        M = nm;
    }
    loss[r] = M + logf(Ssum) - tl[r];
}

// ================================================================ host launcher
extern "C" void kernel_launch(void* const* d_in, const int* in_sizes, int n_in,
                              void* d_out, int out_size, void* d_ws, size_t ws_size,
                              hipStream_t stream)
{
    const int*   tokens = (const int*)d_in[0];
    const float* emb    = (const float*)d_in[1];
    const float* Wih_s  = (const float*)d_in[2];
    const float* Whh_s  = (const float*)d_in[3];
    const float* bih_s  = (const float*)d_in[4];
    const float* bhh_s  = (const float*)d_in[5];
    const float* Wih_f  = (const float*)d_in[6];
    const float* Whh_f  = (const float*)d_in[7];
    const float* bih_f  = (const float*)d_in[8];
    const float* bhh_f  = (const float*)d_in[9];
    const float* Wih_b  = (const float*)d_in[10];
    const float* Whh_b  = (const float*)d_in[11];
    const float* bih_b  = (const float*)d_in[12];
    const float* bhh_b  = (const float*)d_in[13];
    const float* Wc     = (const float*)d_in[14];
    const float* bc     = (const float*)d_in[15];
    const float* Wout   = (const float*)d_in[16];
    const float* bout   = (const float*)d_in[17];
    float* loss = (float*)d_out;

    float* ws = (float*)d_ws;
    size_t off = 0;
    float* e    = ws + off; off += (size_t)T_ * B_ * S_;   // 2,097,152
    float* hF   = ws + off; off += (size_t)GB_ * S_;       // zero region start
    float* cF   = ws + off; off += (size_t)GB_ * S_;
    float* hB   = ws + off; off += (size_t)GB_ * S_;
    float* cB   = ws + off; off += (size_t)GB_ * S_;
    float* hs0  = ws + off; off += (size_t)B_ * S_;
    float* hs1  = ws + off; off += (size_t)B_ * S_;
    float* cs   = ws + off; off += (size_t)B_ * S_;        // zero region end
    float* zbuf = ws + off; off += (size_t)2 * GB_ * S4_;
    float* comp = ws + off; off += (size_t)GB_ * S_;
    float* hp   = ws + off; off += (size_t)T_ * B_ * S_;
    float* pmax = ws + off; off += (size_t)T_ * B_ * NT_LSE_;
    float* psum = ws + off; off += (size_t)T_ * B_ * NT_LSE_;
    float* tl   = ws + off; off += (size_t)T_ * B_;

    // zero LSTM states (ws is re-poisoned to 0xAA before every call)
    size_t zero_bytes = ((size_t)4 * GB_ * S_ + (size_t)3 * B_ * S_) * sizeof(float);
    hipMemsetAsync(hF, 0, zero_bytes, stream);

    k_gather<<<T_ * B_, 128, 0, stream>>>(tokens, emb, e);

    for (int k = 0; k < 8; ++k) {
        k_compose_z<<<dim3(32, 8, 2), 256, 0, stream>>>(
            e, hF, hB, Wih_f, Whh_f, bih_f, bhh_f,
            Wih_b, Whh_b, bih_b, bhh_b, zbuf, k);
        k_compose_gates<<<2048, 256, 0, stream>>>(zbuf, hF, cF, hB, cB);
    }
    k_comp<<<dim3(8, 8), 256, 0, stream>>>(hF, hB, Wc, bc, comp);

    float* hb[2] = { hs0, hs1 };
    for (int i = 0; i < NSTEPS_; ++i) {
        k_stack_step<<<256, 256, 0, stream>>>(e, comp, tokens, emb,
                                              Wih_s, Whh_s, bih_s, bhh_s,
                                              hb[i & 1], hb[(i + 1) & 1], cs, hp, i);
    }

    k_tok<<<T_ * B_, 64, 0, stream>>>(tokens, hp, Wout, bout, tl);
    k_lse<<<dim3(NT_LSE_, 32), 256, 0, stream>>>(hp, Wout, bout, pmax, psum);
    k_final<<<16, 256, 0, stream>>>(pmax, psum, tl, loss);
}

// Round 3
// 7993.520 us; speedup vs baseline: 1.2837x; 1.2837x over previous
//
#include <hip/hip_runtime.h>
#include <math.h>

// Problem constants
static constexpr int S_   = 512;     // hidden size
static constexpr int S4_  = 2048;    // 4*S (gates)
static constexpr int B_   = 16;      // batch
static constexpr int T_   = 256;     // tokens
static constexpr int G_   = 32;      // groups
static constexpr int GB_  = 512;     // G*B compose rows
static constexpr int V_   = 32000;   // vocab
static constexpr int NSTEPS_ = 321;  // 1 + G*(K+2)
static constexpr int NT_LSE_ = 250;  // vocab tiles of 128
static constexpr int SCAN_NB = 64;   // persistent scan blocks
static constexpr int MZX_ = 5184;    // 81*64 padded zx rows (>= 321*16=5136)

__device__ __forceinline__ float sigm(float x) { return 1.0f / (1.0f + expf(-x)); }

// ---------------------------------------------------------------- gather e = emb[tokens]
__global__ __launch_bounds__(128)
void k_gather(const int* __restrict__ tokens, const float* __restrict__ emb,
              float* __restrict__ e)
{
    int row = blockIdx.x;                 // t*16 + b
    int tok = tokens[row];
    const float4* src = (const float4*)(emb + (size_t)tok * S_);
    float4*       dst = (float4*)(e + (size_t)row * S_);
    dst[threadIdx.x] = src[threadIdx.x];  // 128 float4 = 512 floats
}

// ---------------------------------------------------------------- compose z-GEMM (one step, both dirs)
__global__ __launch_bounds__(256)
void k_compose_z(const float* __restrict__ e,
                 const float* __restrict__ hF, const float* __restrict__ hB,
                 const float* __restrict__ Wih_f, const float* __restrict__ Whh_f,
                 const float* __restrict__ bih_f, const float* __restrict__ bhh_f,
                 const float* __restrict__ Wih_b, const float* __restrict__ Whh_b,
                 const float* __restrict__ bih_b, const float* __restrict__ bhh_b,
                 float* __restrict__ zbuf, int stepk)
{
    __shared__ float As[16][64];
    __shared__ float Bs[16][64];
    const int d  = blockIdx.z;
    const int Mb = blockIdx.y * 64;
    const int Nb = blockIdx.x * 64;
    const int t  = threadIdx.x;

    const float* Wih = d ? Wih_b : Wih_f;
    const float* Whh = d ? Whh_b : Whh_f;
    const float* bih = d ? bih_b : bih_f;
    const float* bhh = d ? bhh_b : bhh_f;
    const float* h   = d ? hB : hF;
    const int child  = d ? (7 - stepk) : stepk;

    const int ml = t & 63;
    const int ko = (t >> 6) * 4;
    const int m  = Mb + ml;
    const int g  = m >> 4, b = m & 15;
    const float* xrow = e + ((size_t)((g * 8 + child) * 16 + b)) * S_;
    const float* hrow = h + (size_t)m * S_;
    const int n  = Nb + ml;
    const float* wi = Wih + (size_t)n * S_;
    const float* wh = Whh + (size_t)n * S_;

    const int tx = t & 15, ty = t >> 4;
    float acc[4][4] = {};

    for (int kk = 0; kk < 1024; kk += 16) {
        const float* ar = (kk < 512) ? (xrow + kk + ko) : (hrow + kk - 512 + ko);
        const float* br = (kk < 512) ? (wi + kk + ko)   : (wh + kk - 512 + ko);
        float4 av = *(const float4*)ar;
        float4 bv = *(const float4*)br;
        __syncthreads();
        As[ko + 0][ml] = av.x; As[ko + 1][ml] = av.y; As[ko + 2][ml] = av.z; As[ko + 3][ml] = av.w;
        Bs[ko + 0][ml] = bv.x; Bs[ko + 1][ml] = bv.y; Bs[ko + 2][ml] = bv.z; Bs[ko + 3][ml] = bv.w;
        __syncthreads();
#pragma unroll
        for (int k = 0; k < 16; ++k) {
            float a[4], bb[4];
#pragma unroll
            for (int i = 0; i < 4; ++i) a[i]  = As[k][ty * 4 + i];
#pragma unroll
            for (int j = 0; j < 4; ++j) bb[j] = Bs[k][tx * 4 + j];
#pragma unroll
            for (int i = 0; i < 4; ++i)
#pragma unroll
                for (int j = 0; j < 4; ++j) acc[i][j] += a[i] * bb[j];
        }
    }
#pragma unroll
    for (int i = 0; i < 4; ++i) {
        int mm = Mb + ty * 4 + i;
#pragma unroll
        for (int j = 0; j < 4; ++j) {
            int nn = Nb + tx * 4 + j;
            zbuf[((size_t)(d * 512 + mm)) * S4_ + nn] = acc[i][j] + bih[nn] + bhh[nn];
        }
    }
}

// ---------------------------------------------------------------- compose gate update
__global__ __launch_bounds__(256)
void k_compose_gates(const float* __restrict__ zbuf,
                     float* __restrict__ hF, float* __restrict__ cF,
                     float* __restrict__ hB, float* __restrict__ cB)
{
    int idx = blockIdx.x * 256 + threadIdx.x;  // 2*512*512
    int d   = idx >> 18;
    int rem = idx & ((1 << 18) - 1);
    int gb  = rem >> 9;
    int u   = rem & 511;
    const float* z = zbuf + ((size_t)(d * 512 + gb)) * S4_;
    float zi = z[u], zf = z[u + 512], zg = z[u + 1024], zo = z[u + 1536];
    float* hptr = d ? hB : hF;
    float* cptr = d ? cB : cF;
    float c = cptr[gb * S_ + u];
    c = sigm(zf) * c + sigm(zi) * tanhf(zg);
    hptr[gb * S_ + u] = sigm(zo) * tanhf(c);
    cptr[gb * S_ + u] = c;
}

// ---------------------------------------------------------------- comp = tanh([hF|hB] @ Wc.T + bc)
__global__ __launch_bounds__(256)
void k_comp(const float* __restrict__ hF, const float* __restrict__ hB,
            const float* __restrict__ Wc, const float* __restrict__ bc,
            float* __restrict__ comp)
{
    __shared__ float As[16][64];
    __shared__ float Bs[16][64];
    const int Mb = blockIdx.y * 64;
    const int Nb = blockIdx.x * 64;
    const int t  = threadIdx.x;
    const int ml = t & 63;
    const int ko = (t >> 6) * 4;
    const int m  = Mb + ml;
    const float* fr = hF + (size_t)m * S_;
    const float* br_ = hB + (size_t)m * S_;
    const int n  = Nb + ml;
    const float* wr = Wc + (size_t)n * 1024;
    const int tx = t & 15, ty = t >> 4;
    float acc[4][4] = {};

    for (int kk = 0; kk < 1024; kk += 16) {
        const float* ar = (kk < 512) ? (fr + kk + ko) : (br_ + kk - 512 + ko);
        float4 av = *(const float4*)ar;
        float4 bv = *(const float4*)(wr + kk + ko);
        __syncthreads();
        As[ko + 0][ml] = av.x; As[ko + 1][ml] = av.y; As[ko + 2][ml] = av.z; As[ko + 3][ml] = av.w;
        Bs[ko + 0][ml] = bv.x; Bs[ko + 1][ml] = bv.y; Bs[ko + 2][ml] = bv.z; Bs[ko + 3][ml] = bv.w;
        __syncthreads();
#pragma unroll
        for (int k = 0; k < 16; ++k) {
            float a[4], bb[4];
#pragma unroll
            for (int i = 0; i < 4; ++i) a[i]  = As[k][ty * 4 + i];
#pragma unroll
            for (int j = 0; j < 4; ++j) bb[j] = Bs[k][tx * 4 + j];
#pragma unroll
            for (int i = 0; i < 4; ++i)
#pragma unroll
                for (int j = 0; j < 4; ++j) acc[i][j] += a[i] * bb[j];
        }
    }
#pragma unroll
    for (int i = 0; i < 4; ++i) {
        int mm = Mb + ty * 4 + i;
#pragma unroll
        for (int j = 0; j < 4; ++j) {
            int nn = Nb + tx * 4 + j;
            comp[(size_t)mm * S_ + nn] = tanhf(acc[i][j] + bc[nn]);
        }
    }
}

// ---------------------------------------------------------------- zx = x_step @ Wih_s.T + bih_s + bhh_s
// M = 5184 (padded; row = step*16+b), N = 2048, K = 512
__global__ __launch_bounds__(256)
void k_zx(const int* __restrict__ tokens, const float* __restrict__ emb,
          const float* __restrict__ e, const float* __restrict__ comp,
          const float* __restrict__ Wih, const float* __restrict__ bih,
          const float* __restrict__ bhh, float* __restrict__ zx)
{
    __shared__ float As[16][64];
    __shared__ float Bs[16][64];
    const int Mb = blockIdx.y * 64;
    const int Nb = blockIdx.x * 64;
    const int t  = threadIdx.x;
    const int ml = t & 63;
    const int ko = (t >> 6) * 4;

    int m = Mb + ml;
    int s = m >> 4; if (s > 320) s = 320;
    int b = m & 15;
    const float* xrow;
    if (s == 0) xrow = emb + (size_t)tokens[0] * S_;
    else {
        int j = s - 1, g = j / 10, r = j - g * 10;
        if (r == 0)      xrow = emb + (size_t)tokens[0] * S_;
        else if (r <= 8) xrow = e + ((size_t)((g * 8 + r - 1) * 16 + b)) * S_;
        else             xrow = comp + ((size_t)(g * 16 + b)) * S_;
    }
    const int n = Nb + ml;
    const float* wr = Wih + (size_t)n * S_;
    const int tx = t & 15, ty = t >> 4;
    float acc[4][4] = {};

    for (int kk = 0; kk < 512; kk += 16) {
        float4 av = *(const float4*)(xrow + kk + ko);
        float4 bv = *(const float4*)(wr + kk + ko);
        __syncthreads();
        As[ko + 0][ml] = av.x; As[ko + 1][ml] = av.y; As[ko + 2][ml] = av.z; As[ko + 3][ml] = av.w;
        Bs[ko + 0][ml] = bv.x; Bs[ko + 1][ml] = bv.y; Bs[ko + 2][ml] = bv.z; Bs[ko + 3][ml] = bv.w;
        __syncthreads();
#pragma unroll
        for (int k = 0; k < 16; ++k) {
            float a[4], bb[4];
#pragma unroll
            for (int i = 0; i < 4; ++i) a[i]  = As[k][ty * 4 + i];
#pragma unroll
            for (int j = 0; j < 4; ++j) bb[j] = Bs[k][tx * 4 + j];
#pragma unroll
            for (int i = 0; i < 4; ++i)
#pragma unroll
                for (int j = 0; j < 4; ++j) acc[i][j] += a[i] * bb[j];
        }
    }
#pragma unroll
    for (int i = 0; i < 4; ++i) {
        int mm = Mb + ty * 4 + i;
#pragma unroll
        for (int j = 0; j < 4; ++j) {
            int nn = Nb + tx * 4 + j;
            zx[(size_t)mm * S4_ + nn] = acc[i][j] + bih[nn] + bhh[nn];
        }
    }
}

// ---------------------------------------------------------------- persistent stack-LSTM scan
// 64 blocks x 256 threads, 1 block/CU (LDS ~113 KB). Block owns 8 units (all 4 gates).
// Whh slice pre-arranged in LDS (wlin) in exact per-lane read order (bank-spread).
// h ping-pongs through global hg[2][16][512]; device-scope flag barrier per step.
__global__ __launch_bounds__(256)
void k_scan(const float* __restrict__ zx, const float* __restrict__ Whh,
            float* __restrict__ hg, float* __restrict__ hp,
            int* __restrict__ flags)
{
    __shared__ float4 wlin[8 * 513];          // [kc][k4*32 + j*8 + nq]
    __shared__ float4 hlin[8 * 257];          // [kc][k4*16 + i*4 + bq]
    __shared__ float  zred[8][32 * 17];       // [kc][pt*17 + i*4 + j]
    const int t  = threadIdx.x;
    const int u0 = (int)blockIdx.x * 8;

    // one-time: build wlin from Whh rows n = gate*512 + u0 + ui  (lr = gate*8+ui = nq*4+j)
#pragma unroll 4
    for (int q = 0; q < 16; ++q) {
        int v  = t * 16 + q;                  // 4096 float4 slots
        int kc = v >> 9, r = v & 511;         // r = k4*32 + j*8 + nq
        int k4 = r >> 5, rr = r & 31;
        int j  = rr >> 3, nq = rr & 7;
        int lr = nq * 4 + j;
        int n  = (lr >> 3) * 512 + u0 + (lr & 7);
        int k  = kc * 64 + k4 * 4;
        wlin[kc * 513 + r] = *(const float4*)(Whh + (size_t)n * S_ + k);
    }

    const int kc = t >> 5;                    // 0..7  (k-chunk of 64)
    const int pt = t & 31;
    const int bq = pt >> 3;                   // 0..3  (4 batch rows each)
    const int nq = pt & 7;                    // 0..7  (4 n-rows each)
    const int hbase = kc * 257 + bq;
    const int wbase = kc * 513 + nq;

    const int gb_b  = t >> 3;                 // gate phase (t<128)
    const int gb_ui = t & 7;
    float creg = 0.0f;

    for (int s = 0; s < NSTEPS_; ++s) {
        // stage h(s-1) -> hlin (hg zeroed at s=0)
        {
            int b = t >> 4;
            int kbase = (t & 15) * 32;
            const float* src = hg + (s & 1) * 8192 + b * S_ + kbase;
#pragma unroll
            for (int q = 0; q < 8; ++q) {
                int k = kbase + q * 4;
                float4 v = *(const float4*)(src + q * 4);
                hlin[(k >> 6) * 257 + ((k & 63) >> 2) * 16 + (b >> 2) + (b & 3) * 4] = v;
            }
        }
        __syncthreads();
        // micro-GEMM: 4b x 4n per thread over 64 k
        float acc[4][4] = {{0.f,0.f,0.f,0.f},{0.f,0.f,0.f,0.f},{0.f,0.f,0.f,0.f},{0.f,0.f,0.f,0.f}};
#pragma unroll
        for (int k4 = 0; k4 < 16; ++k4) {
            float4 hv[4], wv[4];
#pragma unroll
            for (int i = 0; i < 4; ++i) hv[i] = hlin[hbase + k4 * 16 + i * 4];
#pragma unroll
            for (int j = 0; j < 4; ++j) wv[j] = wlin[wbase + k4 * 32 + j * 8];
#pragma unroll
            for (int i = 0; i < 4; ++i)
#pragma unroll
                for (int j = 0; j < 4; ++j)
                    acc[i][j] += hv[i].x * wv[j].x + hv[i].y * wv[j].y
                               + hv[i].z * wv[j].z + hv[i].w * wv[j].w;
        }
#pragma unroll
        for (int i = 0; i < 4; ++i)
#pragma unroll
            for (int j = 0; j < 4; ++j)
                zred[kc][pt * 17 + i * 4 + j] = acc[i][j];
        __syncthreads();
        // gates: t<128: (b = t>>3, ui = t&7)
        if (t < 128) {
            float z[4];
#pragma unroll
            for (int g = 0; g < 4; ++g) {
                int lr  = g * 8 + gb_ui;
                int idx = ((gb_b >> 2) * 8 + (lr >> 2)) * 17 + (gb_b & 3) * 4 + (lr & 3);
                float sum = zred[0][idx];
#pragma unroll
                for (int c = 1; c < 8; ++c) sum += zred[c][idx];
                z[g] = zx[((size_t)(s * 16 + gb_b)) * S4_ + g * 512 + u0 + gb_ui] + sum;
            }
            creg = sigm(z[1]) * creg + sigm(z[0]) * tanhf(z[2]);
            float hh = sigm(z[3]) * tanhf(creg);
            hg[((s + 1) & 1) * 8192 + gb_b * S_ + u0 + gb_ui] = hh;
            if (s >= 1) {
                int j2 = s - 1, g2 = j2 / 10, r = j2 - g2 * 10;
                if (r <= 7)
                    hp[((size_t)((g2 * 8 + r) * 16 + gb_b)) * S_ + u0 + gb_ui] = hh;
            }
        }
        __threadfence();
        __syncthreads();
        if (t == 0)
            __hip_atomic_store(&flags[blockIdx.x * 32], s + 1,
                               __ATOMIC_RELEASE, __HIP_MEMORY_SCOPE_AGENT);
        if (t < SCAN_NB) {
            while (__hip_atomic_load(&flags[t * 32], __ATOMIC_ACQUIRE,
                                     __HIP_MEMORY_SCOPE_AGENT) < s + 1) {
                __builtin_amdgcn_s_sleep(1);
            }
        }
        __threadfence();
        __syncthreads();
    }
}

// ---------------------------------------------------------------- legacy per-step stack kernel (ws fallback)
__global__ __launch_bounds__(256)
void k_stack_step(const float* __restrict__ e, const float* __restrict__ comp,
                  const int* __restrict__ tokens, const float* __restrict__ emb,
                  const float* __restrict__ Wih, const float* __restrict__ Whh,
                  const float* __restrict__ bih, const float* __restrict__ bhh,
                  const float* __restrict__ hsrc, float* __restrict__ hdst,
                  float* __restrict__ cst, float* __restrict__ hp, int step)
{
    __shared__ float zsh[128];
    const int t    = threadIdx.x;
    const int p    = t >> 1, half = t & 1;
    const int b    = p >> 3, rest = p & 7;
    const int ul   = rest >> 2, gate = rest & 3;
    const int unit = blockIdx.x * 2 + ul;
    const int n    = gate * 512 + unit;

    const float* row;
    if (half == 0) {
        const float* xs;
        if (step == 0) xs = emb + (size_t)tokens[0] * S_;
        else {
            int j = step - 1, g = j / 10, r = j - g * 10;
            if (r == 0)      xs = emb + (size_t)tokens[0] * S_;
            else if (r <= 8) xs = e + ((size_t)((g * 8 + r - 1) * 16 + b)) * S_;
            else             xs = comp + ((size_t)(g * 16 + b)) * S_;
        }
        row = xs;
    } else {
        row = hsrc + (size_t)b * S_;
    }
    const float* w = (half == 0 ? Wih : Whh) + (size_t)n * S_;

    const float4* r4 = (const float4*)row;
    const float4* w4 = (const float4*)w;
    float ax = 0.f, ay = 0.f, az = 0.f, aw = 0.f;
#pragma unroll 8
    for (int q = 0; q < 128; ++q) {
        float4 a = r4[q], ww = w4[q];
        ax += a.x * ww.x; ay += a.y * ww.y; az += a.z * ww.z; aw += a.w * ww.w;
    }
    float s = (ax + ay) + (az + aw);
    float o = __shfl_xor(s, 1);
    if (half == 0) zsh[p] = s + o + bih[n] + bhh[n];
    __syncthreads();

    if (t < 32) {
        int b2   = t >> 1;
        int u2   = blockIdx.x * 2 + (t & 1);
        int base = b2 * 8 + (t & 1) * 4;
        float zi = zsh[base + 0], zf = zsh[base + 1], zg = zsh[base + 2], zo = zsh[base + 3];
        float c  = cst[b2 * S_ + u2];
        c = sigm(zf) * c + sigm(zi) * tanhf(zg);
        float hh = sigm(zo) * tanhf(c);
        cst[b2 * S_ + u2]  = c;
        hdst[b2 * S_ + u2] = hh;
        if (step >= 1) {
            int j = step - 1, g = j / 10, r = j - g * 10;
            if (r <= 7) {
                int tt = g * 8 + r;
                hp[((size_t)(tt * 16 + b2)) * S_ + u2] = hh;
            }
        }
    }
}

// ---------------------------------------------------------------- token logit (one wave per row)
__global__ __launch_bounds__(64)
void k_tok(const int* __restrict__ tokens, const float* __restrict__ hp,
           const float* __restrict__ Wout, const float* __restrict__ bout,
           float* __restrict__ tl)
{
    int row  = blockIdx.x;
    int lane = threadIdx.x;
    int tok  = tokens[row];
    const float4* a = (const float4*)(hp + (size_t)row * S_);
    const float4* w = (const float4*)(Wout + (size_t)tok * S_);
    float s = 0.f;
    for (int q = lane; q < 128; q += 64) {
        float4 av = a[q], wv = w[q];
        s += av.x * wv.x + av.y * wv.y + av.z * wv.z + av.w * wv.w;
    }
    for (int off = 32; off; off >>= 1) s += __shfl_down(s, off);
    if (lane == 0) tl[row] = s + bout[tok];
}

// ---------------------------------------------------------------- logits GEMM + online LSE partials
__global__ __launch_bounds__(256)
void k_lse(const float* __restrict__ hp, const float* __restrict__ Wout,
           const float* __restrict__ bout, float* __restrict__ pmax,
           float* __restrict__ psum)
{
    __shared__ float As[16][128];
    __shared__ float Bs[16][128];
    __shared__ float red[128][17];
    __shared__ float rmax[128];
    const int Nb = blockIdx.x * 128;   // 250 tiles
    const int Mb = blockIdx.y * 128;   // 32 tiles
    const int t  = threadIdx.x;
    const int ml = t & 127, ko = (t >> 7) * 8;
    const float* arow = hp   + (size_t)(Mb + ml) * S_;
    const float* brow = Wout + (size_t)(Nb + ml) * S_;
    const int tx = t & 15, ty = t >> 4;
    float acc[8][8] = {};

    for (int kk = 0; kk < 512; kk += 16) {
        float4 a0 = *(const float4*)(arow + kk + ko);
        float4 a1 = *(const float4*)(arow + kk + ko + 4);
        float4 b0 = *(const float4*)(brow + kk + ko);
        float4 b1 = *(const float4*)(brow + kk + ko + 4);
        __syncthreads();
        As[ko + 0][ml] = a0.x; As[ko + 1][ml] = a0.y; As[ko + 2][ml] = a0.z; As[ko + 3][ml] = a0.w;
        As[ko + 4][ml] = a1.x; As[ko + 5][ml] = a1.y; As[ko + 6][ml] = a1.z; As[ko + 7][ml] = a1.w;
        Bs[ko + 0][ml] = b0.x; Bs[ko + 1][ml] = b0.y; Bs[ko + 2][ml] = b0.z; Bs[ko + 3][ml] = b0.w;
        Bs[ko + 4][ml] = b1.x; Bs[ko + 5][ml] = b1.y; Bs[ko + 6][ml] = b1.z; Bs[ko + 7][ml] = b1.w;
        __syncthreads();
#pragma unroll
        for (int k = 0; k < 16; ++k) {
            float a[8], bb[8];
#pragma unroll
            for (int i = 0; i < 8; ++i) a[i]  = As[k][ty * 8 + i];
#pragma unroll
            for (int j = 0; j < 8; ++j) bb[j] = Bs[k][tx * 8 + j];
#pragma unroll
            for (int i = 0; i < 8; ++i)
#pragma unroll
                for (int j = 0; j < 8; ++j) acc[i][j] += a[i] * bb[j];
        }
    }

    float bv[8];
#pragma unroll
    for (int j = 0; j < 8; ++j) bv[j] = bout[Nb + tx * 8 + j];

#pragma unroll
    for (int i = 0; i < 8; ++i) {
        float m = -INFINITY;
#pragma unroll
        for (int j = 0; j < 8; ++j) m = fmaxf(m, acc[i][j] + bv[j]);
        red[ty * 8 + i][tx] = m;
    }
    __syncthreads();
    if (t < 128) {
        float m = red[t][0];
#pragma unroll
        for (int x = 1; x < 16; ++x) m = fmaxf(m, red[t][x]);
        rmax[t] = m;
    }
    __syncthreads();
#pragma unroll
    for (int i = 0; i < 8; ++i) {
        float m = rmax[ty * 8 + i];
        float ss = 0.f;
#pragma unroll
        for (int j = 0; j < 8; ++j) ss += expf(acc[i][j] + bv[j] - m);
        red[ty * 8 + i][tx] = ss;
    }
    __syncthreads();
    if (t < 128) {
        float ss = 0.f;
#pragma unroll
        for (int x = 0; x < 16; ++x) ss += red[t][x];
        size_t off = (size_t)(Mb + t) * NT_LSE_ + blockIdx.x;
        pmax[off] = rmax[t];
        psum[off] = ss;
    }
}

// ---------------------------------------------------------------- final reduce: loss = LSE - tok_logit
__global__ __launch_bounds__(256)
void k_final(const float* __restrict__ pmax, const float* __restrict__ psum,
             const float* __restrict__ tl, float* __restrict__ loss)
{
    int r = blockIdx.x * 256 + threadIdx.x;  // 4096 rows
    const float* pm = pmax + (size_t)r * NT_LSE_;
    const float* ps = psum + (size_t)r * NT_LSE_;
    float M = -INFINITY, Ssum = 0.f;
    for (int nt = 0; nt < NT_LSE_; ++nt) {
        float m2 = pm[nt], s2 = ps[nt];
        float nm = fmaxf(M, m2);
        Ssum = Ssum * expf(M - nm) + s2 * expf(m2 - nm);
        M = nm;
    }
    loss[r] = M + logf(Ssum) - tl[r];
}

// ================================================================ host launcher
extern "C" void kernel_launch(void* const* d_in, const int* in_sizes, int n_in,
                              void* d_out, int out_size, void* d_ws, size_t ws_size,
                              hipStream_t stream)
{
    const int*   tokens = (const int*)d_in[0];
    const float* emb    = (const float*)d_in[1];
    const float* Wih_s  = (const float*)d_in[2];
    const float* Whh_s  = (const float*)d_in[3];
    const float* bih_s  = (const float*)d_in[4];
    const float* bhh_s  = (const float*)d_in[5];
    const float* Wih_f  = (const float*)d_in[6];
    const float* Whh_f  = (const float*)d_in[7];
    const float* bih_f  = (const float*)d_in[8];
    const float* bhh_f  = (const float*)d_in[9];
    const float* Wih_b  = (const float*)d_in[10];
    const float* Whh_b  = (const float*)d_in[11];
    const float* bih_b  = (const float*)d_in[12];
    const float* bhh_b  = (const float*)d_in[13];
    const float* Wc     = (const float*)d_in[14];
    const float* bc     = (const float*)d_in[15];
    const float* Wout   = (const float*)d_in[16];
    const float* bout   = (const float*)d_in[17];
    float* loss = (float*)d_out;

    float* ws = (float*)d_ws;

    // ---- persistent-path layout
    size_t off = 0;
    float* e    = ws + off; off += (size_t)T_ * B_ * S_;
    float* hF   = ws + off; off += (size_t)GB_ * S_;       // zero region start
    float* cF   = ws + off; off += (size_t)GB_ * S_;
    float* hB   = ws + off; off += (size_t)GB_ * S_;
    float* cB   = ws + off; off += (size_t)GB_ * S_;
    float* hg   = ws + off; off += (size_t)2 * B_ * S_;
    int*   flags = (int*)(ws + off); off += (size_t)SCAN_NB * 32;  // zero region end
    size_t zero_end = off;
    float* zbuf = ws + off; off += (size_t)2 * GB_ * S4_;
    float* comp = ws + off; off += (size_t)GB_ * S_;
    float* hp   = ws + off; off += (size_t)T_ * B_ * S_;
    float* pmax = ws + off; off += (size_t)T_ * B_ * NT_LSE_;
    float* psum = ws + off; off += (size_t)T_ * B_ * NT_LSE_;
    float* tl   = ws + off; off += (size_t)T_ * B_;
    float* zx   = ws + off; off += (size_t)MZX_ * S4_;
    size_t need_bytes = off * sizeof(float);

    if (ws_size >= need_bytes) {
        // zero: hF..flags
        size_t zs = (size_t)T_ * B_ * S_;
        hipMemsetAsync(hF, 0, (zero_end - zs) * sizeof(float), stream);

        k_gather<<<T_ * B_, 128, 0, stream>>>(tokens, emb, e);
        for (int k = 0; k < 8; ++k) {
            k_compose_z<<<dim3(32, 8, 2), 256, 0, stream>>>(
                e, hF, hB, Wih_f, Whh_f, bih_f, bhh_f,
                Wih_b, Whh_b, bih_b, bhh_b, zbuf, k);
            k_compose_gates<<<2048, 256, 0, stream>>>(zbuf, hF, cF, hB, cB);
        }
        k_comp<<<dim3(8, 8), 256, 0, stream>>>(hF, hB, Wc, bc, comp);
        k_zx<<<dim3(32, 81), 256, 0, stream>>>(tokens, emb, e, comp,
                                               Wih_s, bih_s, bhh_s, zx);
        k_scan<<<SCAN_NB, 256, 0, stream>>>(zx, Whh_s, hg, hp, flags);

        k_tok<<<T_ * B_, 64, 0, stream>>>(tokens, hp, Wout, bout, tl);
        k_lse<<<dim3(NT_LSE_, 32), 256, 0, stream>>>(hp, Wout, bout, pmax, psum);
        k_final<<<16, 256, 0, stream>>>(pmax, psum, tl, loss);
    } else {
        // ---- legacy fallback layout (proven path)
        off = 0;
        float* e2    = ws + off; off += (size_t)T_ * B_ * S_;
        float* hF2   = ws + off; off += (size_t)GB_ * S_;
        float* cF2   = ws + off; off += (size_t)GB_ * S_;
        float* hB2   = ws + off; off += (size_t)GB_ * S_;
        float* cB2   = ws + off; off += (size_t)GB_ * S_;
        float* hs0   = ws + off; off += (size_t)B_ * S_;
        float* hs1   = ws + off; off += (size_t)B_ * S_;
        float* cs    = ws + off; off += (size_t)B_ * S_;
        float* zbuf2 = ws + off; off += (size_t)2 * GB_ * S4_;
        float* comp2 = ws + off; off += (size_t)GB_ * S_;
        float* hp2   = ws + off; off += (size_t)T_ * B_ * S_;
        float* pmax2 = ws + off; off += (size_t)T_ * B_ * NT_LSE_;
        float* psum2 = ws + off; off += (size_t)T_ * B_ * NT_LSE_;
        float* tl2   = ws + off; off += (size_t)T_ * B_;

        size_t zero_bytes = ((size_t)4 * GB_ * S_ + (size_t)3 * B_ * S_) * sizeof(float);
        hipMemsetAsync(hF2, 0, zero_bytes, stream);

        k_gather<<<T_ * B_, 128, 0, stream>>>(tokens, emb, e2);
        for (int k = 0; k < 8; ++k) {
            k_compose_z<<<dim3(32, 8, 2), 256, 0, stream>>>(
                e2, hF2, hB2, Wih_f, Whh_f, bih_f, bhh_f,
                Wih_b, Whh_b, bih_b, bhh_b, zbuf2, k);
            k_compose_gates<<<2048, 256, 0, stream>>>(zbuf2, hF2, cF2, hB2, cB2);
        }
        k_comp<<<dim3(8, 8), 256, 0, stream>>>(hF2, hB2, Wc, bc, comp2);

        float* hb[2] = { hs0, hs1 };
        for (int i = 0; i < NSTEPS_; ++i) {
            k_stack_step<<<256, 256, 0, stream>>>(e2, comp2, tokens, emb,
                                                  Wih_s, Whh_s, bih_s, bhh_s,
                                                  hb[i & 1], hb[(i + 1) & 1], cs, hp2, i);
        }
        k_tok<<<T_ * B_, 64, 0, stream>>>(tokens, hp2, Wout, bout, tl2);
        k_lse<<<dim3(NT_LSE_, 32), 256, 0, stream>>>(hp2, Wout, bout, pmax2, psum2);
        k_final<<<16, 256, 0, stream>>>(pmax2, psum2, tl2, loss);
    }
}

// Round 4
// 5693.344 us; speedup vs baseline: 1.8024x; 1.4040x over previous
//
#include <hip/hip_runtime.h>
#include <math.h>

// Problem constants
static constexpr int S_   = 512;     // hidden size
static constexpr int S4_  = 2048;    // 4*S (gates)
static constexpr int B_   = 16;      // batch
static constexpr int T_   = 256;     // tokens
static constexpr int G_   = 32;      // groups
static constexpr int GB_  = 512;     // G*B compose rows
static constexpr int V_   = 32000;   // vocab
static constexpr int NSTEPS_ = 321;  // 1 + G*(K+2)
static constexpr int NT_LSE_ = 250;  // vocab tiles of 128
static constexpr int SCAN_NB = 64;   // persistent scan blocks
static constexpr int MZX_ = 5184;    // 81*64 padded zx rows (>= 321*16=5136)

__device__ __forceinline__ float sigm(float x) { return 1.0f / (1.0f + expf(-x)); }

// ---------------------------------------------------------------- gather e = emb[tokens]
__global__ __launch_bounds__(128)
void k_gather(const int* __restrict__ tokens, const float* __restrict__ emb,
              float* __restrict__ e)
{
    int row = blockIdx.x;                 // t*16 + b
    int tok = tokens[row];
    const float4* src = (const float4*)(emb + (size_t)tok * S_);
    float4*       dst = (float4*)(e + (size_t)row * S_);
    dst[threadIdx.x] = src[threadIdx.x];  // 128 float4 = 512 floats
}

// ---------------------------------------------------------------- compose z-GEMM (one step, both dirs)
__global__ __launch_bounds__(256)
void k_compose_z(const float* __restrict__ e,
                 const float* __restrict__ hF, const float* __restrict__ hB,
                 const float* __restrict__ Wih_f, const float* __restrict__ Whh_f,
                 const float* __restrict__ bih_f, const float* __restrict__ bhh_f,
                 const float* __restrict__ Wih_b, const float* __restrict__ Whh_b,
                 const float* __restrict__ bih_b, const float* __restrict__ bhh_b,
                 float* __restrict__ zbuf, int stepk)
{
    __shared__ float As[16][64];
    __shared__ float Bs[16][64];
    const int d  = blockIdx.z;
    const int Mb = blockIdx.y * 64;
    const int Nb = blockIdx.x * 64;
    const int t  = threadIdx.x;

    const float* Wih = d ? Wih_b : Wih_f;
    const float* Whh = d ? Whh_b : Whh_f;
    const float* bih = d ? bih_b : bih_f;
    const float* bhh = d ? bhh_b : bhh_f;
    const float* h   = d ? hB : hF;
    const int child  = d ? (7 - stepk) : stepk;

    const int ml = t & 63;
    const int ko = (t >> 6) * 4;
    const int m  = Mb + ml;
    const int g  = m >> 4, b = m & 15;
    const float* xrow = e + ((size_t)((g * 8 + child) * 16 + b)) * S_;
    const float* hrow = h + (size_t)m * S_;
    const int n  = Nb + ml;
    const float* wi = Wih + (size_t)n * S_;
    const float* wh = Whh + (size_t)n * S_;

    const int tx = t & 15, ty = t >> 4;
    float acc[4][4] = {};

    for (int kk = 0; kk < 1024; kk += 16) {
        const float* ar = (kk < 512) ? (xrow + kk + ko) : (hrow + kk - 512 + ko);
        const float* br = (kk < 512) ? (wi + kk + ko)   : (wh + kk - 512 + ko);
        float4 av = *(const float4*)ar;
        float4 bv = *(const float4*)br;
        __syncthreads();
        As[ko + 0][ml] = av.x; As[ko + 1][ml] = av.y; As[ko + 2][ml] = av.z; As[ko + 3][ml] = av.w;
        Bs[ko + 0][ml] = bv.x; Bs[ko + 1][ml] = bv.y; Bs[ko + 2][ml] = bv.z; Bs[ko + 3][ml] = bv.w;
        __syncthreads();
#pragma unroll
        for (int k = 0; k < 16; ++k) {
            float a[4], bb[4];
#pragma unroll
            for (int i = 0; i < 4; ++i) a[i]  = As[k][ty * 4 + i];
#pragma unroll
            for (int j = 0; j < 4; ++j) bb[j] = Bs[k][tx * 4 + j];
#pragma unroll
            for (int i = 0; i < 4; ++i)
#pragma unroll
                for (int j = 0; j < 4; ++j) acc[i][j] += a[i] * bb[j];
        }
    }
#pragma unroll
    for (int i = 0; i < 4; ++i) {
        int mm = Mb + ty * 4 + i;
#pragma unroll
        for (int j = 0; j < 4; ++j) {
            int nn = Nb + tx * 4 + j;
            zbuf[((size_t)(d * 512 + mm)) * S4_ + nn] = acc[i][j] + bih[nn] + bhh[nn];
        }
    }
}

// ---------------------------------------------------------------- compose gate update
__global__ __launch_bounds__(256)
void k_compose_gates(const float* __restrict__ zbuf,
                     float* __restrict__ hF, float* __restrict__ cF,
                     float* __restrict__ hB, float* __restrict__ cB)
{
    int idx = blockIdx.x * 256 + threadIdx.x;  // 2*512*512
    int d   = idx >> 18;
    int rem = idx & ((1 << 18) - 1);
    int gb  = rem >> 9;
    int u   = rem & 511;
    const float* z = zbuf + ((size_t)(d * 512 + gb)) * S4_;
    float zi = z[u], zf = z[u + 512], zg = z[u + 1024], zo = z[u + 1536];
    float* hptr = d ? hB : hF;
    float* cptr = d ? cB : cF;
    float c = cptr[gb * S_ + u];
    c = sigm(zf) * c + sigm(zi) * tanhf(zg);
    hptr[gb * S_ + u] = sigm(zo) * tanhf(c);
    cptr[gb * S_ + u] = c;
}

// ---------------------------------------------------------------- comp = tanh([hF|hB] @ Wc.T + bc)
__global__ __launch_bounds__(256)
void k_comp(const float* __restrict__ hF, const float* __restrict__ hB,
            const float* __restrict__ Wc, const float* __restrict__ bc,
            float* __restrict__ comp)
{
    __shared__ float As[16][64];
    __shared__ float Bs[16][64];
    const int Mb = blockIdx.y * 64;
    const int Nb = blockIdx.x * 64;
    const int t  = threadIdx.x;
    const int ml = t & 63;
    const int ko = (t >> 6) * 4;
    const int m  = Mb + ml;
    const float* fr = hF + (size_t)m * S_;
    const float* br_ = hB + (size_t)m * S_;
    const int n  = Nb + ml;
    const float* wr = Wc + (size_t)n * 1024;
    const int tx = t & 15, ty = t >> 4;
    float acc[4][4] = {};

    for (int kk = 0; kk < 1024; kk += 16) {
        const float* ar = (kk < 512) ? (fr + kk + ko) : (br_ + kk - 512 + ko);
        float4 av = *(const float4*)ar;
        float4 bv = *(const float4*)(wr + kk + ko);
        __syncthreads();
        As[ko + 0][ml] = av.x; As[ko + 1][ml] = av.y; As[ko + 2][ml] = av.z; As[ko + 3][ml] = av.w;
        Bs[ko + 0][ml] = bv.x; Bs[ko + 1][ml] = bv.y; Bs[ko + 2][ml] = bv.z; Bs[ko + 3][ml] = bv.w;
        __syncthreads();
#pragma unroll
        for (int k = 0; k < 16; ++k) {
            float a[4], bb[4];
#pragma unroll
            for (int i = 0; i < 4; ++i) a[i]  = As[k][ty * 4 + i];
#pragma unroll
            for (int j = 0; j < 4; ++j) bb[j] = Bs[k][tx * 4 + j];
#pragma unroll
            for (int i = 0; i < 4; ++i)
#pragma unroll
                for (int j = 0; j < 4; ++j) acc[i][j] += a[i] * bb[j];
        }
    }
#pragma unroll
    for (int i = 0; i < 4; ++i) {
        int mm = Mb + ty * 4 + i;
#pragma unroll
        for (int j = 0; j < 4; ++j) {
            int nn = Nb + tx * 4 + j;
            comp[(size_t)mm * S_ + nn] = tanhf(acc[i][j] + bc[nn]);
        }
    }
}

// ---------------------------------------------------------------- zx = x_step @ Wih_s.T + bih_s + bhh_s
// M = 5184 (padded; row = step*16+b), N = 2048, K = 512
__global__ __launch_bounds__(256)
void k_zx(const int* __restrict__ tokens, const float* __restrict__ emb,
          const float* __restrict__ e, const float* __restrict__ comp,
          const float* __restrict__ Wih, const float* __restrict__ bih,
          const float* __restrict__ bhh, float* __restrict__ zx)
{
    __shared__ float As[16][64];
    __shared__ float Bs[16][64];
    const int Mb = blockIdx.y * 64;
    const int Nb = blockIdx.x * 64;
    const int t  = threadIdx.x;
    const int ml = t & 63;
    const int ko = (t >> 6) * 4;

    int m = Mb + ml;
    int s = m >> 4; if (s > 320) s = 320;
    int b = m & 15;
    const float* xrow;
    if (s == 0) xrow = emb + (size_t)tokens[0] * S_;
    else {
        int j = s - 1, g = j / 10, r = j - g * 10;
        if (r == 0)      xrow = emb + (size_t)tokens[0] * S_;
        else if (r <= 8) xrow = e + ((size_t)((g * 8 + r - 1) * 16 + b)) * S_;
        else             xrow = comp + ((size_t)(g * 16 + b)) * S_;
    }
    const int n = Nb + ml;
    const float* wr = Wih + (size_t)n * S_;
    const int tx = t & 15, ty = t >> 4;
    float acc[4][4] = {};

    for (int kk = 0; kk < 512; kk += 16) {
        float4 av = *(const float4*)(xrow + kk + ko);
        float4 bv = *(const float4*)(wr + kk + ko);
        __syncthreads();
        As[ko + 0][ml] = av.x; As[ko + 1][ml] = av.y; As[ko + 2][ml] = av.z; As[ko + 3][ml] = av.w;
        Bs[ko + 0][ml] = bv.x; Bs[ko + 1][ml] = bv.y; Bs[ko + 2][ml] = bv.z; Bs[ko + 3][ml] = bv.w;
        __syncthreads();
#pragma unroll
        for (int k = 0; k < 16; ++k) {
            float a[4], bb[4];
#pragma unroll
            for (int i = 0; i < 4; ++i) a[i]  = As[k][ty * 4 + i];
#pragma unroll
            for (int j = 0; j < 4; ++j) bb[j] = Bs[k][tx * 4 + j];
#pragma unroll
            for (int i = 0; i < 4; ++i)
#pragma unroll
                for (int j = 0; j < 4; ++j) acc[i][j] += a[i] * bb[j];
        }
    }
#pragma unroll
    for (int i = 0; i < 4; ++i) {
        int mm = Mb + ty * 4 + i;
#pragma unroll
        for (int j = 0; j < 4; ++j) {
            int nn = Nb + tx * 4 + j;
            zx[(size_t)mm * S4_ + nn] = acc[i][j] + bih[nn] + bhh[nn];
        }
    }
}

// ---------------------------------------------------------------- persistent stack-LSTM scan
// 64 blocks x 256 threads, 1 block/CU (LDS ~113 KB). Block owns 8 units (all 4 gates).
// Whh slice pre-arranged in LDS (wlin); zx/Whh on the normal cached path.
// Cross-block h exchange + flags use RELAXED agent-scope atomics ONLY (lower to
// sc0/sc1 coherent loads/stores at the MALL — NO L2-wide invalidate/writeback,
// unlike ACQUIRE/RELEASE/threadfence which cost ~15.8 us/step in round 3).
// Producer ordering: per-wave s_waitcnt vmcnt(0) + __syncthreads before flag store.
__global__ __launch_bounds__(256)
void k_scan(const float* __restrict__ zx, const float* __restrict__ Whh,
            float* __restrict__ hg, float* __restrict__ hp,
            int* __restrict__ flags)
{
    __shared__ float4 wlin[8 * 513];          // [kc][k4*32 + j*8 + nq]
    __shared__ float4 hlin[8 * 257];          // [kc][k4*16 + i*4 + bq]
    __shared__ float  zred[8][32 * 17];       // [kc][pt*17 + i*4 + j]
    const int t  = threadIdx.x;
    const int u0 = (int)blockIdx.x * 8;

    // one-time: build wlin from Whh rows n = gate*512 + u0 + ui  (lr = gate*8+ui = nq*4+j)
#pragma unroll 4
    for (int q = 0; q < 16; ++q) {
        int v  = t * 16 + q;                  // 4096 float4 slots
        int kc = v >> 9, r = v & 511;         // r = k4*32 + j*8 + nq
        int k4 = r >> 5, rr = r & 31;
        int j  = rr >> 3, nq = rr & 7;
        int lr = nq * 4 + j;
        int n  = (lr >> 3) * 512 + u0 + (lr & 7);
        int k  = kc * 64 + k4 * 4;
        wlin[kc * 513 + r] = *(const float4*)(Whh + (size_t)n * S_ + k);
    }

    const int kc = t >> 5;                    // 0..7  (k-chunk of 64)
    const int pt = t & 31;
    const int bq = pt >> 3;                   // 0..3  (4 batch rows each)
    const int nq = pt & 7;                    // 0..7  (4 n-rows each)
    const int hbase = kc * 257 + bq;
    const int wbase = kc * 513 + nq;

    const int gb_b  = t >> 3;                 // gate phase (t<128)
    const int gb_ui = t & 7;
    float creg = 0.0f;

    for (int s = 0; s < NSTEPS_; ++s) {
        // (1) issue this step's zx gate loads early (cached path; latency hides
        //     under spin + h-stage + GEMM; zx never invalidated now -> L2-warm)
        float zxr[4];
        if (t < 128) {
#pragma unroll
            for (int g = 0; g < 4; ++g)
                zxr[g] = zx[((size_t)(s * 16 + gb_b)) * S4_ + g * 512 + u0 + gb_ui];
        }
        // (2) wait until all blocks finished step s-1 (h_{s-1} at MALL)
        if (s > 0) {
            if (t < SCAN_NB) {
                while (__hip_atomic_load(&flags[t * 32], __ATOMIC_RELAXED,
                                         __HIP_MEMORY_SCOPE_AGENT) < s) {
                    __builtin_amdgcn_s_sleep(1);
                }
            }
            __syncthreads();
        }
        // (3) stage h(s-1) -> hlin via coherent (MALL) loads; hg[0] zeroed for s=0
        {
            int b = t >> 4;
            int kbase = (t & 15) * 32;
            const float* src = hg + (s & 1) * 8192 + b * S_ + kbase;
#pragma unroll
            for (int q = 0; q < 8; ++q) {
                int k = kbase + q * 4;
                float4 v;
                v.x = __hip_atomic_load(src + q * 4 + 0, __ATOMIC_RELAXED, __HIP_MEMORY_SCOPE_AGENT);
                v.y = __hip_atomic_load(src + q * 4 + 1, __ATOMIC_RELAXED, __HIP_MEMORY_SCOPE_AGENT);
                v.z = __hip_atomic_load(src + q * 4 + 2, __ATOMIC_RELAXED, __HIP_MEMORY_SCOPE_AGENT);
                v.w = __hip_atomic_load(src + q * 4 + 3, __ATOMIC_RELAXED, __HIP_MEMORY_SCOPE_AGENT);
                hlin[(k >> 6) * 257 + ((k & 63) >> 2) * 16 + (b >> 2) + (b & 3) * 4] = v;
            }
        }
        __syncthreads();
        // (4) micro-GEMM: 4b x 4n per thread over 64 k
        float acc[4][4] = {{0.f,0.f,0.f,0.f},{0.f,0.f,0.f,0.f},{0.f,0.f,0.f,0.f},{0.f,0.f,0.f,0.f}};
#pragma unroll
        for (int k4 = 0; k4 < 16; ++k4) {
            float4 hv[4], wv[4];
#pragma unroll
            for (int i = 0; i < 4; ++i) hv[i] = hlin[hbase + k4 * 16 + i * 4];
#pragma unroll
            for (int j = 0; j < 4; ++j) wv[j] = wlin[wbase + k4 * 32 + j * 8];
#pragma unroll
            for (int i = 0; i < 4; ++i)
#pragma unroll
                for (int j = 0; j < 4; ++j)
                    acc[i][j] += hv[i].x * wv[j].x + hv[i].y * wv[j].y
                               + hv[i].z * wv[j].z + hv[i].w * wv[j].w;
        }
#pragma unroll
        for (int i = 0; i < 4; ++i)
#pragma unroll
            for (int j = 0; j < 4; ++j)
                zred[kc][pt * 17 + i * 4 + j] = acc[i][j];
        __syncthreads();
        // (5) gates: t<128: (b = t>>3, ui = t&7)
        if (t < 128) {
            float z[4];
#pragma unroll
            for (int g = 0; g < 4; ++g) {
                int lr  = g * 8 + gb_ui;
                int idx = ((gb_b >> 2) * 8 + (lr >> 2)) * 17 + (gb_b & 3) * 4 + (lr & 3);
                float sum = zred[0][idx];
#pragma unroll
                for (int c = 1; c < 8; ++c) sum += zred[c][idx];
                z[g] = zxr[g] + sum;
            }
            creg = sigm(z[1]) * creg + sigm(z[0]) * tanhf(z[2]);
            float hh = sigm(z[3]) * tanhf(creg);
            __hip_atomic_store(&hg[((s + 1) & 1) * 8192 + gb_b * S_ + u0 + gb_ui], hh,
                               __ATOMIC_RELAXED, __HIP_MEMORY_SCOPE_AGENT);
            if (s >= 1) {
                int j2 = s - 1, g2 = j2 / 10, r = j2 - g2 * 10;
                if (r <= 7)
                    hp[((size_t)((g2 * 8 + r) * 16 + gb_b)) * S_ + u0 + gb_ui] = hh;
            }
        }
        // (6) drain this wave's coherent stores (vmcnt retires at MALL ack),
        //     sync all waves, then publish step completion (relaxed is enough).
        asm volatile("s_waitcnt vmcnt(0)" ::: "memory");
        __syncthreads();
        if (t == 0)
            __hip_atomic_store(&flags[blockIdx.x * 32], s + 1,
                               __ATOMIC_RELAXED, __HIP_MEMORY_SCOPE_AGENT);
    }
}

// ---------------------------------------------------------------- legacy per-step stack kernel (ws fallback)
__global__ __launch_bounds__(256)
void k_stack_step(const float* __restrict__ e, const float* __restrict__ comp,
                  const int* __restrict__ tokens, const float* __restrict__ emb,
                  const float* __restrict__ Wih, const float* __restrict__ Whh,
                  const float* __restrict__ bih, const float* __restrict__ bhh,
                  const float* __restrict__ hsrc, float* __restrict__ hdst,
                  float* __restrict__ cst, float* __restrict__ hp, int step)
{
    __shared__ float zsh[128];
    const int t    = threadIdx.x;
    const int p    = t >> 1, half = t & 1;
    const int b    = p >> 3, rest = p & 7;
    const int ul   = rest >> 2, gate = rest & 3;
    const int unit = blockIdx.x * 2 + ul;
    const int n    = gate * 512 + unit;

    const float* row;
    if (half == 0) {
        const float* xs;
        if (step == 0) xs = emb + (size_t)tokens[0] * S_;
        else {
            int j = step - 1, g = j / 10, r = j - g * 10;
            if (r == 0)      xs = emb + (size_t)tokens[0] * S_;
            else if (r <= 8) xs = e + ((size_t)((g * 8 + r - 1) * 16 + b)) * S_;
            else             xs = comp + ((size_t)(g * 16 + b)) * S_;
        }
        row = xs;
    } else {
        row = hsrc + (size_t)b * S_;
    }
    const float* w = (half == 0 ? Wih : Whh) + (size_t)n * S_;

    const float4* r4 = (const float4*)row;
    const float4* w4 = (const float4*)w;
    float ax = 0.f, ay = 0.f, az = 0.f, aw = 0.f;
#pragma unroll 8
    for (int q = 0; q < 128; ++q) {
        float4 a = r4[q], ww = w4[q];
        ax += a.x * ww.x; ay += a.y * ww.y; az += a.z * ww.z; aw += a.w * ww.w;
    }
    float s = (ax + ay) + (az + aw);
    float o = __shfl_xor(s, 1);
    if (half == 0) zsh[p] = s + o + bih[n] + bhh[n];
    __syncthreads();

    if (t < 32) {
        int b2   = t >> 1;
        int u2   = blockIdx.x * 2 + (t & 1);
        int base = b2 * 8 + (t & 1) * 4;
        float zi = zsh[base + 0], zf = zsh[base + 1], zg = zsh[base + 2], zo = zsh[base + 3];
        float c  = cst[b2 * S_ + u2];
        c = sigm(zf) * c + sigm(zi) * tanhf(zg);
        float hh = sigm(zo) * tanhf(c);
        cst[b2 * S_ + u2]  = c;
        hdst[b2 * S_ + u2] = hh;
        if (step >= 1) {
            int j = step - 1, g = j / 10, r = j - g * 10;
            if (r <= 7) {
                int tt = g * 8 + r;
                hp[((size_t)(tt * 16 + b2)) * S_ + u2] = hh;
            }
        }
    }
}

// ---------------------------------------------------------------- token logit (one wave per row)
__global__ __launch_bounds__(64)
void k_tok(const int* __restrict__ tokens, const float* __restrict__ hp,
           const float* __restrict__ Wout, const float* __restrict__ bout,
           float* __restrict__ tl)
{
    int row  = blockIdx.x;
    int lane = threadIdx.x;
    int tok  = tokens[row];
    const float4* a = (const float4*)(hp + (size_t)row * S_);
    const float4* w = (const float4*)(Wout + (size_t)tok * S_);
    float s = 0.f;
    for (int q = lane; q < 128; q += 64) {
        float4 av = a[q], wv = w[q];
        s += av.x * wv.x + av.y * wv.y + av.z * wv.z + av.w * wv.w;
    }
    for (int off = 32; off; off >>= 1) s += __shfl_down(s, off);
    if (lane == 0) tl[row] = s + bout[tok];
}

// ---------------------------------------------------------------- logits GEMM + online LSE partials
__global__ __launch_bounds__(256)
void k_lse(const float* __restrict__ hp, const float* __restrict__ Wout,
           const float* __restrict__ bout, float* __restrict__ pmax,
           float* __restrict__ psum)
{
    __shared__ float As[16][128];
    __shared__ float Bs[16][128];
    __shared__ float red[128][17];
    __shared__ float rmax[128];
    const int Nb = blockIdx.x * 128;   // 250 tiles
    const int Mb = blockIdx.y * 128;   // 32 tiles
    const int t  = threadIdx.x;
    const int ml = t & 127, ko = (t >> 7) * 8;
    const float* arow = hp   + (size_t)(Mb + ml) * S_;
    const float* brow = Wout + (size_t)(Nb + ml) * S_;
    const int tx = t & 15, ty = t >> 4;
    float acc[8][8] = {};

    for (int kk = 0; kk < 512; kk += 16) {
        float4 a0 = *(const float4*)(arow + kk + ko);
        float4 a1 = *(const float4*)(arow + kk + ko + 4);
        float4 b0 = *(const float4*)(brow + kk + ko);
        float4 b1 = *(const float4*)(brow + kk + ko + 4);
        __syncthreads();
        As[ko + 0][ml] = a0.x; As[ko + 1][ml] = a0.y; As[ko + 2][ml] = a0.z; As[ko + 3][ml] = a0.w;
        As[ko + 4][ml] = a1.x; As[ko + 5][ml] = a1.y; As[ko + 6][ml] = a1.z; As[ko + 7][ml] = a1.w;
        Bs[ko + 0][ml] = b0.x; Bs[ko + 1][ml] = b0.y; Bs[ko + 2][ml] = b0.z; Bs[ko + 3][ml] = b0.w;
        Bs[ko + 4][ml] = b1.x; Bs[ko + 5][ml] = b1.y; Bs[ko + 6][ml] = b1.z; Bs[ko + 7][ml] = b1.w;
        __syncthreads();
#pragma unroll
        for (int k = 0; k < 16; ++k) {
            float a[8], bb[8];
#pragma unroll
            for (int i = 0; i < 8; ++i) a[i]  = As[k][ty * 8 + i];
#pragma unroll
            for (int j = 0; j < 8; ++j) bb[j] = Bs[k][tx * 8 + j];
#pragma unroll
            for (int i = 0; i < 8; ++i)
#pragma unroll
                for (int j = 0; j < 8; ++j) acc[i][j] += a[i] * bb[j];
        }
    }

    float bv[8];
#pragma unroll
    for (int j = 0; j < 8; ++j) bv[j] = bout[Nb + tx * 8 + j];

#pragma unroll
    for (int i = 0; i < 8; ++i) {
        float m = -INFINITY;
#pragma unroll
        for (int j = 0; j < 8; ++j) m = fmaxf(m, acc[i][j] + bv[j]);
        red[ty * 8 + i][tx] = m;
    }
    __syncthreads();
    if (t < 128) {
        float m = red[t][0];
#pragma unroll
        for (int x = 1; x < 16; ++x) m = fmaxf(m, red[t][x]);
        rmax[t] = m;
    }
    __syncthreads();
#pragma unroll
    for (int i = 0; i < 8; ++i) {
        float m = rmax[ty * 8 + i];
        float ss = 0.f;
#pragma unroll
        for (int j = 0; j < 8; ++j) ss += expf(acc[i][j] + bv[j] - m);
        red[ty * 8 + i][tx] = ss;
    }
    __syncthreads();
    if (t < 128) {
        float ss = 0.f;
#pragma unroll
        for (int x = 0; x < 16; ++x) ss += red[t][x];
        size_t off = (size_t)(Mb + t) * NT_LSE_ + blockIdx.x;
        pmax[off] = rmax[t];
        psum[off] = ss;
    }
}

// ---------------------------------------------------------------- final reduce: loss = LSE - tok_logit
__global__ __launch_bounds__(256)
void k_final(const float* __restrict__ pmax, const float* __restrict__ psum,
             const float* __restrict__ tl, float* __restrict__ loss)
{
    int r = blockIdx.x * 256 + threadIdx.x;  // 4096 rows
    const float* pm = pmax + (size_t)r * NT_LSE_;
    const float* ps = psum + (size_t)r * NT_LSE_;
    float M = -INFINITY, Ssum = 0.f;
    for (int nt = 0; nt < NT_LSE_; ++nt) {
        float m2 = pm[nt], s2 = ps[nt];
        float nm = fmaxf(M, m2);
        Ssum = Ssum * expf(M - nm) + s2 * expf(m2 - nm);
        M = nm;
    }
    loss[r] = M + logf(Ssum) - tl[r];
}

// ================================================================ host launcher
extern "C" void kernel_launch(void* const* d_in, const int* in_sizes, int n_in,
                              void* d_out, int out_size, void* d_ws, size_t ws_size,
                              hipStream_t stream)
{
    const int*   tokens = (const int*)d_in[0];
    const float* emb    = (const float*)d_in[1];
    const float* Wih_s  = (const float*)d_in[2];
    const float* Whh_s  = (const float*)d_in[3];
    const float* bih_s  = (const float*)d_in[4];
    const float* bhh_s  = (const float*)d_in[5];
    const float* Wih_f  = (const float*)d_in[6];
    const float* Whh_f  = (const float*)d_in[7];
    const float* bih_f  = (const float*)d_in[8];
    const float* bhh_f  = (const float*)d_in[9];
    const float* Wih_b  = (const float*)d_in[10];
    const float* Whh_b  = (const float*)d_in[11];
    const float* bih_b  = (const float*)d_in[12];
    const float* bhh_b  = (const float*)d_in[13];
    const float* Wc     = (const float*)d_in[14];
    const float* bc     = (const float*)d_in[15];
    const float* Wout   = (const float*)d_in[16];
    const float* bout   = (const float*)d_in[17];
    float* loss = (float*)d_out;

    float* ws = (float*)d_ws;

    // ---- persistent-path layout
    size_t off = 0;
    float* e    = ws + off; off += (size_t)T_ * B_ * S_;
    float* hF   = ws + off; off += (size_t)GB_ * S_;       // zero region start
    float* cF   = ws + off; off += (size_t)GB_ * S_;
    float* hB   = ws + off; off += (size_t)GB_ * S_;
    float* cB   = ws + off; off += (size_t)GB_ * S_;
    float* hg   = ws + off; off += (size_t)2 * B_ * S_;
    int*   flags = (int*)(ws + off); off += (size_t)SCAN_NB * 32;  // zero region end
    size_t zero_end = off;
    float* zbuf = ws + off; off += (size_t)2 * GB_ * S4_;
    float* comp = ws + off; off += (size_t)GB_ * S_;
    float* hp   = ws + off; off += (size_t)T_ * B_ * S_;
    float* pmax = ws + off; off += (size_t)T_ * B_ * NT_LSE_;
    float* psum = ws + off; off += (size_t)T_ * B_ * NT_LSE_;
    float* tl   = ws + off; off += (size_t)T_ * B_;
    float* zx   = ws + off; off += (size_t)MZX_ * S4_;
    size_t need_bytes = off * sizeof(float);

    if (ws_size >= need_bytes) {
        // zero: hF..flags
        size_t zs = (size_t)T_ * B_ * S_;
        hipMemsetAsync(hF, 0, (zero_end - zs) * sizeof(float), stream);

        k_gather<<<T_ * B_, 128, 0, stream>>>(tokens, emb, e);
        for (int k = 0; k < 8; ++k) {
            k_compose_z<<<dim3(32, 8, 2), 256, 0, stream>>>(
                e, hF, hB, Wih_f, Whh_f, bih_f, bhh_f,
                Wih_b, Whh_b, bih_b, bhh_b, zbuf, k);
            k_compose_gates<<<2048, 256, 0, stream>>>(zbuf, hF, cF, hB, cB);
        }
        k_comp<<<dim3(8, 8), 256, 0, stream>>>(hF, hB, Wc, bc, comp);
        k_zx<<<dim3(32, 81), 256, 0, stream>>>(tokens, emb, e, comp,
                                               Wih_s, bih_s, bhh_s, zx);
        k_scan<<<SCAN_NB, 256, 0, stream>>>(zx, Whh_s, hg, hp, flags);

        k_tok<<<T_ * B_, 64, 0, stream>>>(tokens, hp, Wout, bout, tl);
        k_lse<<<dim3(NT_LSE_, 32), 256, 0, stream>>>(hp, Wout, bout, pmax, psum);
        k_final<<<16, 256, 0, stream>>>(pmax, psum, tl, loss);
    } else {
        // ---- legacy fallback layout (proven path)
        off = 0;
        float* e2    = ws + off; off += (size_t)T_ * B_ * S_;
        float* hF2   = ws + off; off += (size_t)GB_ * S_;
        float* cF2   = ws + off; off += (size_t)GB_ * S_;
        float* hB2   = ws + off; off += (size_t)GB_ * S_;
        float* cB2   = ws + off; off += (size_t)GB_ * S_;
        float* hs0   = ws + off; off += (size_t)B_ * S_;
        float* hs1   = ws + off; off += (size_t)B_ * S_;
        float* cs    = ws + off; off += (size_t)B_ * S_;
        float* zbuf2 = ws + off; off += (size_t)2 * GB_ * S4_;
        float* comp2 = ws + off; off += (size_t)GB_ * S_;
        float* hp2   = ws + off; off += (size_t)T_ * B_ * S_;
        float* pmax2 = ws + off; off += (size_t)T_ * B_ * NT_LSE_;
        float* psum2 = ws + off; off += (size_t)T_ * B_ * NT_LSE_;
        float* tl2   = ws + off; off += (size_t)T_ * B_;

        size_t zero_bytes = ((size_t)4 * GB_ * S_ + (size_t)3 * B_ * S_) * sizeof(float);
        hipMemsetAsync(hF2, 0, zero_bytes, stream);

        k_gather<<<T_ * B_, 128, 0, stream>>>(tokens, emb, e2);
        for (int k = 0; k < 8; ++k) {
            k_compose_z<<<dim3(32, 8, 2), 256, 0, stream>>>(
                e2, hF2, hB2, Wih_f, Whh_f, bih_f, bhh_f,
                Wih_b, Whh_b, bih_b, bhh_b, zbuf2, k);
            k_compose_gates<<<2048, 256, 0, stream>>>(zbuf2, hF2, cF2, hB2, cB2);
        }
        k_comp<<<dim3(8, 8), 256, 0, stream>>>(hF2, hB2, Wc, bc, comp2);

        float* hb[2] = { hs0, hs1 };
        for (int i = 0; i < NSTEPS_; ++i) {
            k_stack_step<<<256, 256, 0, stream>>>(e2, comp2, tokens, emb,
                                                  Wih_s, Whh_s, bih_s, bhh_s,
                                                  hb[i & 1], hb[(i + 1) & 1], cs, hp2, i);
        }
        k_tok<<<T_ * B_, 64, 0, stream>>>(tokens, hp2, Wout, bout, tl2);
        k_lse<<<dim3(NT_LSE_, 32), 256, 0, stream>>>(hp2, Wout, bout, pmax2, psum2);
        k_final<<<16, 256, 0, stream>>>(pmax2, psum2, tl2, loss);
    }
}

// Round 5
// 5002.377 us; speedup vs baseline: 2.0513x; 1.1381x over previous
//
#include <hip/hip_runtime.h>
#include <math.h>

// Problem constants
static constexpr int S_   = 512;     // hidden size
static constexpr int S4_  = 2048;    // 4*S (gates)
static constexpr int B_   = 16;      // batch
static constexpr int T_   = 256;     // tokens
static constexpr int G_   = 32;      // groups
static constexpr int GB_  = 512;     // G*B compose rows
static constexpr int V_   = 32000;   // vocab
static constexpr int NSTEPS_ = 321;  // 1 + G*(K+2)
static constexpr int NT_LSE_ = 250;  // vocab tiles of 128
static constexpr int SCAN_NB = 64;   // persistent scan blocks
static constexpr int MZX_ = 5184;    // 81*64 padded zx rows (>= 321*16=5136)

__device__ __forceinline__ float sigm(float x) { return 1.0f / (1.0f + expf(-x)); }

// ---------------------------------------------------------------- gather e = emb[tokens]
__global__ __launch_bounds__(128)
void k_gather(const int* __restrict__ tokens, const float* __restrict__ emb,
              float* __restrict__ e)
{
    int row = blockIdx.x;                 // t*16 + b
    int tok = tokens[row];
    const float4* src = (const float4*)(emb + (size_t)tok * S_);
    float4*       dst = (float4*)(e + (size_t)row * S_);
    dst[threadIdx.x] = src[threadIdx.x];  // 128 float4 = 512 floats
}

// ---------------------------------------------------------------- compose z-GEMM (one step, both dirs)
__global__ __launch_bounds__(256)
void k_compose_z(const float* __restrict__ e,
                 const float* __restrict__ hF, const float* __restrict__ hB,
                 const float* __restrict__ Wih_f, const float* __restrict__ Whh_f,
                 const float* __restrict__ bih_f, const float* __restrict__ bhh_f,
                 const float* __restrict__ Wih_b, const float* __restrict__ Whh_b,
                 const float* __restrict__ bih_b, const float* __restrict__ bhh_b,
                 float* __restrict__ zbuf, int stepk)
{
    __shared__ float As[16][64];
    __shared__ float Bs[16][64];
    const int d  = blockIdx.z;
    const int Mb = blockIdx.y * 64;
    const int Nb = blockIdx.x * 64;
    const int t  = threadIdx.x;

    const float* Wih = d ? Wih_b : Wih_f;
    const float* Whh = d ? Whh_b : Whh_f;
    const float* bih = d ? bih_b : bih_f;
    const float* bhh = d ? bhh_b : bhh_f;
    const float* h   = d ? hB : hF;
    const int child  = d ? (7 - stepk) : stepk;

    const int ml = t & 63;
    const int ko = (t >> 6) * 4;
    const int m  = Mb + ml;
    const int g  = m >> 4, b = m & 15;
    const float* xrow = e + ((size_t)((g * 8 + child) * 16 + b)) * S_;
    const float* hrow = h + (size_t)m * S_;
    const int n  = Nb + ml;
    const float* wi = Wih + (size_t)n * S_;
    const float* wh = Whh + (size_t)n * S_;

    const int tx = t & 15, ty = t >> 4;
    float acc[4][4] = {};

    for (int kk = 0; kk < 1024; kk += 16) {
        const float* ar = (kk < 512) ? (xrow + kk + ko) : (hrow + kk - 512 + ko);
        const float* br = (kk < 512) ? (wi + kk + ko)   : (wh + kk - 512 + ko);
        float4 av = *(const float4*)ar;
        float4 bv = *(const float4*)br;
        __syncthreads();
        As[ko + 0][ml] = av.x; As[ko + 1][ml] = av.y; As[ko + 2][ml] = av.z; As[ko + 3][ml] = av.w;
        Bs[ko + 0][ml] = bv.x; Bs[ko + 1][ml] = bv.y; Bs[ko + 2][ml] = bv.z; Bs[ko + 3][ml] = bv.w;
        __syncthreads();
#pragma unroll
        for (int k = 0; k < 16; ++k) {
            float a[4], bb[4];
#pragma unroll
            for (int i = 0; i < 4; ++i) a[i]  = As[k][ty * 4 + i];
#pragma unroll
            for (int j = 0; j < 4; ++j) bb[j] = Bs[k][tx * 4 + j];
#pragma unroll
            for (int i = 0; i < 4; ++i)
#pragma unroll
                for (int j = 0; j < 4; ++j) acc[i][j] += a[i] * bb[j];
        }
    }
#pragma unroll
    for (int i = 0; i < 4; ++i) {
        int mm = Mb + ty * 4 + i;
#pragma unroll
        for (int j = 0; j < 4; ++j) {
            int nn = Nb + tx * 4 + j;
            zbuf[((size_t)(d * 512 + mm)) * S4_ + nn] = acc[i][j] + bih[nn] + bhh[nn];
        }
    }
}

// ---------------------------------------------------------------- compose gate update
__global__ __launch_bounds__(256)
void k_compose_gates(const float* __restrict__ zbuf,
                     float* __restrict__ hF, float* __restrict__ cF,
                     float* __restrict__ hB, float* __restrict__ cB)
{
    int idx = blockIdx.x * 256 + threadIdx.x;  // 2*512*512
    int d   = idx >> 18;
    int rem = idx & ((1 << 18) - 1);
    int gb  = rem >> 9;
    int u   = rem & 511;
    const float* z = zbuf + ((size_t)(d * 512 + gb)) * S4_;
    float zi = z[u], zf = z[u + 512], zg = z[u + 1024], zo = z[u + 1536];
    float* hptr = d ? hB : hF;
    float* cptr = d ? cB : cF;
    float c = cptr[gb * S_ + u];
    c = sigm(zf) * c + sigm(zi) * tanhf(zg);
    hptr[gb * S_ + u] = sigm(zo) * tanhf(c);
    cptr[gb * S_ + u] = c;
}

// ---------------------------------------------------------------- comp = tanh([hF|hB] @ Wc.T + bc)
__global__ __launch_bounds__(256)
void k_comp(const float* __restrict__ hF, const float* __restrict__ hB,
            const float* __restrict__ Wc, const float* __restrict__ bc,
            float* __restrict__ comp)
{
    __shared__ float As[16][64];
    __shared__ float Bs[16][64];
    const int Mb = blockIdx.y * 64;
    const int Nb = blockIdx.x * 64;
    const int t  = threadIdx.x;
    const int ml = t & 63;
    const int ko = (t >> 6) * 4;
    const int m  = Mb + ml;
    const float* fr = hF + (size_t)m * S_;
    const float* br_ = hB + (size_t)m * S_;
    const int n  = Nb + ml;
    const float* wr = Wc + (size_t)n * 1024;
    const int tx = t & 15, ty = t >> 4;
    float acc[4][4] = {};

    for (int kk = 0; kk < 1024; kk += 16) {
        const float* ar = (kk < 512) ? (fr + kk + ko) : (br_ + kk - 512 + ko);
        float4 av = *(const float4*)ar;
        float4 bv = *(const float4*)(wr + kk + ko);
        __syncthreads();
        As[ko + 0][ml] = av.x; As[ko + 1][ml] = av.y; As[ko + 2][ml] = av.z; As[ko + 3][ml] = av.w;
        Bs[ko + 0][ml] = bv.x; Bs[ko + 1][ml] = bv.y; Bs[ko + 2][ml] = bv.z; Bs[ko + 3][ml] = bv.w;
        __syncthreads();
#pragma unroll
        for (int k = 0; k < 16; ++k) {
            float a[4], bb[4];
#pragma unroll
            for (int i = 0; i < 4; ++i) a[i]  = As[k][ty * 4 + i];
#pragma unroll
            for (int j = 0; j < 4; ++j) bb[j] = Bs[k][tx * 4 + j];
#pragma unroll
            for (int i = 0; i < 4; ++i)
#pragma unroll
                for (int j = 0; j < 4; ++j) acc[i][j] += a[i] * bb[j];
        }
    }
#pragma unroll
    for (int i = 0; i < 4; ++i) {
        int mm = Mb + ty * 4 + i;
#pragma unroll
        for (int j = 0; j < 4; ++j) {
            int nn = Nb + tx * 4 + j;
            comp[(size_t)mm * S_ + nn] = tanhf(acc[i][j] + bc[nn]);
        }
    }
}

// ---------------------------------------------------------------- zxt = x_step @ Wih_s.T + bih_s + bhh_s
// Output TRANSPOSED for the scan: zxt[((s*64 + blk)*4 + g)*128 + b*8 + ui]
// so each scan block's per-step gate slice is one contiguous 2KB run.
__global__ __launch_bounds__(256)
void k_zx(const int* __restrict__ tokens, const float* __restrict__ emb,
          const float* __restrict__ e, const float* __restrict__ comp,
          const float* __restrict__ Wih, const float* __restrict__ bih,
          const float* __restrict__ bhh, float* __restrict__ zxt)
{
    __shared__ float As[16][64];
    __shared__ float Bs[16][64];
    const int Mb = blockIdx.y * 64;
    const int Nb = blockIdx.x * 64;
    const int t  = threadIdx.x;
    const int ml = t & 63;
    const int ko = (t >> 6) * 4;

    int m = Mb + ml;
    int s = m >> 4; if (s > 320) s = 320;
    int b = m & 15;
    const float* xrow;
    if (s == 0) xrow = emb + (size_t)tokens[0] * S_;
    else {
        int j = s - 1, g = j / 10, r = j - g * 10;
        if (r == 0)      xrow = emb + (size_t)tokens[0] * S_;
        else if (r <= 8) xrow = e + ((size_t)((g * 8 + r - 1) * 16 + b)) * S_;
        else             xrow = comp + ((size_t)(g * 16 + b)) * S_;
    }
    const int n = Nb + ml;
    const float* wr = Wih + (size_t)n * S_;
    const int tx = t & 15, ty = t >> 4;
    float acc[4][4] = {};

    for (int kk = 0; kk < 512; kk += 16) {
        float4 av = *(const float4*)(xrow + kk + ko);
        float4 bv = *(const float4*)(wr + kk + ko);
        __syncthreads();
        As[ko + 0][ml] = av.x; As[ko + 1][ml] = av.y; As[ko + 2][ml] = av.z; As[ko + 3][ml] = av.w;
        Bs[ko + 0][ml] = bv.x; Bs[ko + 1][ml] = bv.y; Bs[ko + 2][ml] = bv.z; Bs[ko + 3][ml] = bv.w;
        __syncthreads();
#pragma unroll
        for (int k = 0; k < 16; ++k) {
            float a[4], bb[4];
#pragma unroll
            for (int i = 0; i < 4; ++i) a[i]  = As[k][ty * 4 + i];
#pragma unroll
            for (int j = 0; j < 4; ++j) bb[j] = Bs[k][tx * 4 + j];
#pragma unroll
            for (int i = 0; i < 4; ++i)
#pragma unroll
                for (int j = 0; j < 4; ++j) acc[i][j] += a[i] * bb[j];
        }
    }
#pragma unroll
    for (int i = 0; i < 4; ++i) {
        int mm = Mb + ty * 4 + i;
        int ss = mm >> 4, bb2 = mm & 15;   // padding rows (ss up to 323) still fit
#pragma unroll
        for (int j = 0; j < 4; ++j) {
            int nn = Nb + tx * 4 + j;
            int g = nn >> 9, un = nn & 511;
            zxt[(((size_t)ss * 64 + (un >> 3)) * 4 + g) * 128 + bb2 * 8 + (un & 7)]
                = acc[i][j] + bih[nn] + bhh[nn];
        }
    }
}

// ---------------------------------------------------------------- persistent stack-LSTM scan
// 64 blocks x 256 threads, 1 block/CU. Block owns 8 units (all 4 gates).
// h-chain through a FRESH buffer per step (hseq[s+1]); producers store
// write-through (relaxed agent atomics -> sc0/sc1, visible at MALL);
// consumers read with NORMAL CACHED float4 loads — each hseq address is
// first-touched exactly once per dispatch, so L1/L2 cannot hold stale data
// (round-4 lesson: 32 scalar coherent loads/thread was the barrier cost).
// Completion: one atomicAdd per block on cnt[s]; one lane polls one line.
__global__ __launch_bounds__(256)
void k_scan(const float* __restrict__ zxt, const float* __restrict__ Whh,
            float* __restrict__ hseq,      // [(NSTEPS+1)][16][512]; hseq[0] zeroed
            float* __restrict__ hp, int* __restrict__ cnt)  // cnt[NSTEPS] zeroed
{
    __shared__ float4 wlin[8 * 513];          // [kc][k4*32 + j*8 + nq]
    __shared__ float4 hlin[8 * 257];          // [kc][k4*16 + i*4 + bq]
    __shared__ float  zred[8][32 * 17];       // [kc][pt*17 + i*4 + j]
    const int t  = threadIdx.x;
    const int u0 = (int)blockIdx.x * 8;

    // one-time: build wlin from Whh rows n = gate*512 + u0 + ui  (lr = gate*8+ui = nq*4+j)
#pragma unroll 4
    for (int q = 0; q < 16; ++q) {
        int v  = t * 16 + q;                  // 4096 float4 slots
        int kc = v >> 9, r = v & 511;         // r = k4*32 + j*8 + nq
        int k4 = r >> 5, rr = r & 31;
        int j  = rr >> 3, nq = rr & 7;
        int lr = nq * 4 + j;
        int n  = (lr >> 3) * 512 + u0 + (lr & 7);
        int k  = kc * 64 + k4 * 4;
        wlin[kc * 513 + r] = *(const float4*)(Whh + (size_t)n * S_ + k);
    }

    const int kc = t >> 5;                    // 0..7  (k-chunk of 64)
    const int pt = t & 31;
    const int bq = pt >> 3;                   // 0..3  (4 batch rows each)
    const int nq = pt & 7;                    // 0..7  (4 n-rows each)
    const int hbase = kc * 257 + bq;
    const int wbase = kc * 513 + nq;

    const int gb_b  = t >> 3;                 // gate phase (t<128)
    const int gb_ui = t & 7;
    float creg = 0.0f;

    for (int s = 0; s < NSTEPS_; ++s) {
        // (1) this step's zx gate slice: contiguous 2KB per block, cached path
        float zxr[4];
        if (t < 128) {
            const float* zp = zxt + (((size_t)s * 64 + blockIdx.x) * 4) * 128 + t;
#pragma unroll
            for (int g = 0; g < 4; ++g) zxr[g] = zp[g * 128];
        }
        // (2) wait for all blocks to have published h(s-1)
        if (s > 0) {
            if (t == 0) {
                while (__hip_atomic_load(&cnt[s - 1], __ATOMIC_RELAXED,
                                         __HIP_MEMORY_SCOPE_AGENT) < SCAN_NB) { }
            }
            __syncthreads();
        }
        // (3) stage h(s-1) = hseq[s] -> hlin with normal cached float4 loads
        {
            int b = t >> 4;
            int kbase = (t & 15) * 32;
            const float4* src = (const float4*)(hseq + (size_t)s * 8192 + b * S_ + kbase);
#pragma unroll
            for (int q = 0; q < 8; ++q) {
                int k = kbase + q * 4;
                hlin[(k >> 6) * 257 + ((k & 63) >> 2) * 16 + (b >> 2) + (b & 3) * 4] = src[q];
            }
        }
        __syncthreads();
        // (4) micro-GEMM: 4b x 4n per thread over 64 k
        float acc[4][4] = {{0.f,0.f,0.f,0.f},{0.f,0.f,0.f,0.f},{0.f,0.f,0.f,0.f},{0.f,0.f,0.f,0.f}};
#pragma unroll
        for (int k4 = 0; k4 < 16; ++k4) {
            float4 hv[4], wv[4];
#pragma unroll
            for (int i = 0; i < 4; ++i) hv[i] = hlin[hbase + k4 * 16 + i * 4];
#pragma unroll
            for (int j = 0; j < 4; ++j) wv[j] = wlin[wbase + k4 * 32 + j * 8];
#pragma unroll
            for (int i = 0; i < 4; ++i)
#pragma unroll
                for (int j = 0; j < 4; ++j)
                    acc[i][j] += hv[i].x * wv[j].x + hv[i].y * wv[j].y
                               + hv[i].z * wv[j].z + hv[i].w * wv[j].w;
        }
#pragma unroll
        for (int i = 0; i < 4; ++i)
#pragma unroll
            for (int j = 0; j < 4; ++j)
                zred[kc][pt * 17 + i * 4 + j] = acc[i][j];
        __syncthreads();
        // (5) gates: t<128: (b = t>>3, ui = t&7)
        if (t < 128) {
            float z[4];
#pragma unroll
            for (int g = 0; g < 4; ++g) {
                int lr  = g * 8 + gb_ui;
                int idx = ((gb_b >> 2) * 8 + (lr >> 2)) * 17 + (gb_b & 3) * 4 + (lr & 3);
                float sum = zred[0][idx];
#pragma unroll
                for (int c = 1; c < 8; ++c) sum += zred[c][idx];
                z[g] = zxr[g] + sum;
            }
            creg = sigm(z[1]) * creg + sigm(z[0]) * tanhf(z[2]);
            float hh = sigm(z[3]) * tanhf(creg);
            __hip_atomic_store(&hseq[(size_t)(s + 1) * 8192 + gb_b * S_ + u0 + gb_ui], hh,
                               __ATOMIC_RELAXED, __HIP_MEMORY_SCOPE_AGENT);
            if (s >= 1) {
                int j2 = s - 1, g2 = j2 / 10, r = j2 - g2 * 10;
                if (r <= 7)
                    hp[((size_t)((g2 * 8 + r) * 16 + gb_b)) * S_ + u0 + gb_ui] = hh;
            }
        }
        // (6) drain this wave's stores (write-through acks at coherence point),
        //     sync all waves, then one atomicAdd publishes block completion.
        asm volatile("s_waitcnt vmcnt(0)" ::: "memory");
        __syncthreads();
        if (t == 0)
            __hip_atomic_fetch_add(&cnt[s], 1, __ATOMIC_RELAXED,
                                   __HIP_MEMORY_SCOPE_AGENT);
    }
}

// ---------------------------------------------------------------- legacy per-step stack kernel (ws fallback)
__global__ __launch_bounds__(256)
void k_stack_step(const float* __restrict__ e, const float* __restrict__ comp,
                  const int* __restrict__ tokens, const float* __restrict__ emb,
                  const float* __restrict__ Wih, const float* __restrict__ Whh,
                  const float* __restrict__ bih, const float* __restrict__ bhh,
                  const float* __restrict__ hsrc, float* __restrict__ hdst,
                  float* __restrict__ cst, float* __restrict__ hp, int step)
{
    __shared__ float zsh[128];
    const int t    = threadIdx.x;
    const int p    = t >> 1, half = t & 1;
    const int b    = p >> 3, rest = p & 7;
    const int ul   = rest >> 2, gate = rest & 3;
    const int unit = blockIdx.x * 2 + ul;
    const int n    = gate * 512 + unit;

    const float* row;
    if (half == 0) {
        const float* xs;
        if (step == 0) xs = emb + (size_t)tokens[0] * S_;
        else {
            int j = step - 1, g = j / 10, r = j - g * 10;
            if (r == 0)      xs = emb + (size_t)tokens[0] * S_;
            else if (r <= 8) xs = e + ((size_t)((g * 8 + r - 1) * 16 + b)) * S_;
            else             xs = comp + ((size_t)(g * 16 + b)) * S_;
        }
        row = xs;
    } else {
        row = hsrc + (size_t)b * S_;
    }
    const float* w = (half == 0 ? Wih : Whh) + (size_t)n * S_;

    const float4* r4 = (const float4*)row;
    const float4* w4 = (const float4*)w;
    float ax = 0.f, ay = 0.f, az = 0.f, aw = 0.f;
#pragma unroll 8
    for (int q = 0; q < 128; ++q) {
        float4 a = r4[q], ww = w4[q];
        ax += a.x * ww.x; ay += a.y * ww.y; az += a.z * ww.z; aw += a.w * ww.w;
    }
    float s = (ax + ay) + (az + aw);
    float o = __shfl_xor(s, 1);
    if (half == 0) zsh[p] = s + o + bih[n] + bhh[n];
    __syncthreads();

    if (t < 32) {
        int b2   = t >> 1;
        int u2   = blockIdx.x * 2 + (t & 1);
        int base = b2 * 8 + (t & 1) * 4;
        float zi = zsh[base + 0], zf = zsh[base + 1], zg = zsh[base + 2], zo = zsh[base + 3];
        float c  = cst[b2 * S_ + u2];
        c = sigm(zf) * c + sigm(zi) * tanhf(zg);
        float hh = sigm(zo) * tanhf(c);
        cst[b2 * S_ + u2]  = c;
        hdst[b2 * S_ + u2] = hh;
        if (step >= 1) {
            int j = step - 1, g = j / 10, r = j - g * 10;
            if (r <= 7) {
                int tt = g * 8 + r;
                hp[((size_t)(tt * 16 + b2)) * S_ + u2] = hh;
            }
        }
    }
}

// ---------------------------------------------------------------- token logit (one wave per row)
__global__ __launch_bounds__(64)
void k_tok(const int* __restrict__ tokens, const float* __restrict__ hp,
           const float* __restrict__ Wout, const float* __restrict__ bout,
           float* __restrict__ tl)
{
    int row  = blockIdx.x;
    int lane = threadIdx.x;
    int tok  = tokens[row];
    const float4* a = (const float4*)(hp + (size_t)row * S_);
    const float4* w = (const float4*)(Wout + (size_t)tok * S_);
    float s = 0.f;
    for (int q = lane; q < 128; q += 64) {
        float4 av = a[q], wv = w[q];
        s += av.x * wv.x + av.y * wv.y + av.z * wv.z + av.w * wv.w;
    }
    for (int off = 32; off; off >>= 1) s += __shfl_down(s, off);
    if (lane == 0) tl[row] = s + bout[tok];
}

// ---------------------------------------------------------------- logits GEMM + online LSE partials
__global__ __launch_bounds__(256)
void k_lse(const float* __restrict__ hp, const float* __restrict__ Wout,
           const float* __restrict__ bout, float* __restrict__ pmax,
           float* __restrict__ psum)
{
    __shared__ float As[16][128];
    __shared__ float Bs[16][128];
    __shared__ float red[128][17];
    __shared__ float rmax[128];
    const int Nb = blockIdx.x * 128;   // 250 tiles
    const int Mb = blockIdx.y * 128;   // 32 tiles
    const int t  = threadIdx.x;
    const int ml = t & 127, ko = (t >> 7) * 8;
    const float* arow = hp   + (size_t)(Mb + ml) * S_;
    const float* brow = Wout + (size_t)(Nb + ml) * S_;
    const int tx = t & 15, ty = t >> 4;
    float acc[8][8] = {};

    for (int kk = 0; kk < 512; kk += 16) {
        float4 a0 = *(const float4*)(arow + kk + ko);
        float4 a1 = *(const float4*)(arow + kk + ko + 4);
        float4 b0 = *(const float4*)(brow + kk + ko);
        float4 b1 = *(const float4*)(brow + kk + ko + 4);
        __syncthreads();
        As[ko + 0][ml] = a0.x; As[ko + 1][ml] = a0.y; As[ko + 2][ml] = a0.z; As[ko + 3][ml] = a0.w;
        As[ko + 4][ml] = a1.x; As[ko + 5][ml] = a1.y; As[ko + 6][ml] = a1.z; As[ko + 7][ml] = a1.w;
        Bs[ko + 0][ml] = b0.x; Bs[ko + 1][ml] = b0.y; Bs[ko + 2][ml] = b0.z; Bs[ko + 3][ml] = b0.w;
        Bs[ko + 4][ml] = b1.x; Bs[ko + 5][ml] = b1.y; Bs[ko + 6][ml] = b1.z; Bs[ko + 7][ml] = b1.w;
        __syncthreads();
#pragma unroll
        for (int k = 0; k < 16; ++k) {
            float a[8], bb[8];
#pragma unroll
            for (int i = 0; i < 8; ++i) a[i]  = As[k][ty * 8 + i];
#pragma unroll
            for (int j = 0; j < 8; ++j) bb[j] = Bs[k][tx * 8 + j];
#pragma unroll
            for (int i = 0; i < 8; ++i)
#pragma unroll
                for (int j = 0; j < 8; ++j) acc[i][j] += a[i] * bb[j];
        }
    }

    float bv[8];
#pragma unroll
    for (int j = 0; j < 8; ++j) bv[j] = bout[Nb + tx * 8 + j];

#pragma unroll
    for (int i = 0; i < 8; ++i) {
        float m = -INFINITY;
#pragma unroll
        for (int j = 0; j < 8; ++j) m = fmaxf(m, acc[i][j] + bv[j]);
        red[ty * 8 + i][tx] = m;
    }
    __syncthreads();
    if (t < 128) {
        float m = red[t][0];
#pragma unroll
        for (int x = 1; x < 16; ++x) m = fmaxf(m, red[t][x]);
        rmax[t] = m;
    }
    __syncthreads();
#pragma unroll
    for (int i = 0; i < 8; ++i) {
        float m = rmax[ty * 8 + i];
        float ss = 0.f;
#pragma unroll
        for (int j = 0; j < 8; ++j) ss += expf(acc[i][j] + bv[j] - m);
        red[ty * 8 + i][tx] = ss;
    }
    __syncthreads();
    if (t < 128) {
        float ss = 0.f;
#pragma unroll
        for (int x = 0; x < 16; ++x) ss += red[t][x];
        size_t off = (size_t)(Mb + t) * NT_LSE_ + blockIdx.x;
        pmax[off] = rmax[t];
        psum[off] = ss;
    }
}

// ---------------------------------------------------------------- final reduce: loss = LSE - tok_logit
__global__ __launch_bounds__(256)
void k_final(const float* __restrict__ pmax, const float* __restrict__ psum,
             const float* __restrict__ tl, float* __restrict__ loss)
{
    int r = blockIdx.x * 256 + threadIdx.x;  // 4096 rows
    const float* pm = pmax + (size_t)r * NT_LSE_;
    const float* ps = psum + (size_t)r * NT_LSE_;
    float M = -INFINITY, Ssum = 0.f;
    for (int nt = 0; nt < NT_LSE_; ++nt) {
        float m2 = pm[nt], s2 = ps[nt];
        float nm = fmaxf(M, m2);
        Ssum = Ssum * expf(M - nm) + s2 * expf(m2 - nm);
        M = nm;
    }
    loss[r] = M + logf(Ssum) - tl[r];
}

// ================================================================ host launcher
extern "C" void kernel_launch(void* const* d_in, const int* in_sizes, int n_in,
                              void* d_out, int out_size, void* d_ws, size_t ws_size,
                              hipStream_t stream)
{
    const int*   tokens = (const int*)d_in[0];
    const float* emb    = (const float*)d_in[1];
    const float* Wih_s  = (const float*)d_in[2];
    const float* Whh_s  = (const float*)d_in[3];
    const float* bih_s  = (const float*)d_in[4];
    const float* bhh_s  = (const float*)d_in[5];
    const float* Wih_f  = (const float*)d_in[6];
    const float* Whh_f  = (const float*)d_in[7];
    const float* bih_f  = (const float*)d_in[8];
    const float* bhh_f  = (const float*)d_in[9];
    const float* Wih_b  = (const float*)d_in[10];
    const float* Whh_b  = (const float*)d_in[11];
    const float* bih_b  = (const float*)d_in[12];
    const float* bhh_b  = (const float*)d_in[13];
    const float* Wc     = (const float*)d_in[14];
    const float* bc     = (const float*)d_in[15];
    const float* Wout   = (const float*)d_in[16];
    const float* bout   = (const float*)d_in[17];
    float* loss = (float*)d_out;

    float* ws = (float*)d_ws;

    // ---- persistent-path layout
    size_t off = 0;
    float* e    = ws + off; off += (size_t)T_ * B_ * S_;
    float* hF   = ws + off; off += (size_t)GB_ * S_;       // zero region start
    float* cF   = ws + off; off += (size_t)GB_ * S_;
    float* hB   = ws + off; off += (size_t)GB_ * S_;
    float* cB   = ws + off; off += (size_t)GB_ * S_;
    int*   cnt  = (int*)(ws + off); off += 512;            // NSTEPS counters (zeroed)
    float* hseq = ws + off; off += (size_t)(NSTEPS_ + 1) * B_ * S_;  // hseq[0] zeroed
    size_t zero_end = (size_t)T_ * B_ * S_ + 4 * (size_t)GB_ * S_ + 512 + (size_t)B_ * S_;
    float* zbuf = ws + off; off += (size_t)2 * GB_ * S4_;
    float* comp = ws + off; off += (size_t)GB_ * S_;
    float* hp   = ws + off; off += (size_t)T_ * B_ * S_;
    float* pmax = ws + off; off += (size_t)T_ * B_ * NT_LSE_;
    float* psum = ws + off; off += (size_t)T_ * B_ * NT_LSE_;
    float* tl   = ws + off; off += (size_t)T_ * B_;
    float* zxt  = ws + off; off += (size_t)MZX_ * S4_;
    size_t need_bytes = off * sizeof(float);

    if (ws_size >= need_bytes) {
        // zero: hF..cB, cnt, hseq[0]
        size_t zs = (size_t)T_ * B_ * S_;
        hipMemsetAsync(hF, 0, (zero_end - zs) * sizeof(float), stream);

        k_gather<<<T_ * B_, 128, 0, stream>>>(tokens, emb, e);
        for (int k = 0; k < 8; ++k) {
            k_compose_z<<<dim3(32, 8, 2), 256, 0, stream>>>(
                e, hF, hB, Wih_f, Whh_f, bih_f, bhh_f,
                Wih_b, Whh_b, bih_b, bhh_b, zbuf, k);
            k_compose_gates<<<2048, 256, 0, stream>>>(zbuf, hF, cF, hB, cB);
        }
        k_comp<<<dim3(8, 8), 256, 0, stream>>>(hF, hB, Wc, bc, comp);
        k_zx<<<dim3(32, 81), 256, 0, stream>>>(tokens, emb, e, comp,
                                               Wih_s, bih_s, bhh_s, zxt);
        k_scan<<<SCAN_NB, 256, 0, stream>>>(zxt, Whh_s, hseq, hp, cnt);

        k_tok<<<T_ * B_, 64, 0, stream>>>(tokens, hp, Wout, bout, tl);
        k_lse<<<dim3(NT_LSE_, 32), 256, 0, stream>>>(hp, Wout, bout, pmax, psum);
        k_final<<<16, 256, 0, stream>>>(pmax, psum, tl, loss);
    } else {
        // ---- legacy fallback layout (proven path)
        off = 0;
        float* e2    = ws + off; off += (size_t)T_ * B_ * S_;
        float* hF2   = ws + off; off += (size_t)GB_ * S_;
        float* cF2   = ws + off; off += (size_t)GB_ * S_;
        float* hB2   = ws + off; off += (size_t)GB_ * S_;
        float* cB2   = ws + off; off += (size_t)GB_ * S_;
        float* hs0   = ws + off; off += (size_t)B_ * S_;
        float* hs1   = ws + off; off += (size_t)B_ * S_;
        float* cs    = ws + off; off += (size_t)B_ * S_;
        float* zbuf2 = ws + off; off += (size_t)2 * GB_ * S4_;
        float* comp2 = ws + off; off += (size_t)GB_ * S_;
        float* hp2   = ws + off; off += (size_t)T_ * B_ * S_;
        float* pmax2 = ws + off; off += (size_t)T_ * B_ * NT_LSE_;
        float* psum2 = ws + off; off += (size_t)T_ * B_ * NT_LSE_;
        float* tl2   = ws + off; off += (size_t)T_ * B_;

        size_t zero_bytes = ((size_t)4 * GB_ * S_ + (size_t)3 * B_ * S_) * sizeof(float);
        hipMemsetAsync(hF2, 0, zero_bytes, stream);

        k_gather<<<T_ * B_, 128, 0, stream>>>(tokens, emb, e2);
        for (int k = 0; k < 8; ++k) {
            k_compose_z<<<dim3(32, 8, 2), 256, 0, stream>>>(
                e2, hF2, hB2, Wih_f, Whh_f, bih_f, bhh_f,
                Wih_b, Whh_b, bih_b, bhh_b, zbuf2, k);
            k_compose_gates<<<2048, 256, 0, stream>>>(zbuf2, hF2, cF2, hB2, cB2);
        }
        k_comp<<<dim3(8, 8), 256, 0, stream>>>(hF2, hB2, Wc, bc, comp2);

        float* hb[2] = { hs0, hs1 };
        for (int i = 0; i < NSTEPS_; ++i) {
            k_stack_step<<<256, 256, 0, stream>>>(e2, comp2, tokens, emb,
                                                  Wih_s, Whh_s, bih_s, bhh_s,
                                                  hb[i & 1], hb[(i + 1) & 1], cs, hp2, i);
        }
        k_tok<<<T_ * B_, 64, 0, stream>>>(tokens, hp2, Wout, bout, tl2);
        k_lse<<<dim3(NT_LSE_, 32), 256, 0, stream>>>(hp2, Wout, bout, pmax2, psum2);
        k_final<<<16, 256, 0, stream>>>(pmax2, psum2, tl2, loss);
    }
}

// Round 6
// 3917.579 us; speedup vs baseline: 2.6193x; 1.2769x over previous
//
#include <hip/hip_runtime.h>
#include <math.h>

// Problem constants
static constexpr int S_   = 512;     // hidden size
static constexpr int S4_  = 2048;    // 4*S (gates)
static constexpr int B_   = 16;      // batch
static constexpr int T_   = 256;     // tokens
static constexpr int G_   = 32;      // groups
static constexpr int GB_  = 512;     // G*B compose rows
static constexpr int V_   = 32000;   // vocab
static constexpr int NSTEPS_ = 321;  // 1 + G*(K+2)
static constexpr int NT_LSE_ = 250;  // vocab tiles of 128
static constexpr int SCAN_NB = 64;   // persistent scan blocks
static constexpr int MZX_ = 5184;    // 81*64 padded zx rows (>= 321*16=5136)

typedef __attribute__((ext_vector_type(8))) short bf16x8;
typedef __attribute__((ext_vector_type(4))) float f32x4;

__device__ __forceinline__ float sigm(float x) { return 1.0f / (1.0f + expf(-x)); }

// bf16 round-to-nearest-even (our own approximation choice; reference is fp32)
__device__ __forceinline__ unsigned short f2bf(float x)
{
    unsigned int b = __float_as_uint(x);
    return (unsigned short)((b + 0x7FFFu + ((b >> 16) & 1u)) >> 16);
}

// ---------------------------------------------------------------- gather e = emb[tokens]
__global__ __launch_bounds__(128)
void k_gather(const int* __restrict__ tokens, const float* __restrict__ emb,
              float* __restrict__ e)
{
    int row = blockIdx.x;                 // t*16 + b
    int tok = tokens[row];
    const float4* src = (const float4*)(emb + (size_t)tok * S_);
    float4*       dst = (float4*)(e + (size_t)row * S_);
    dst[threadIdx.x] = src[threadIdx.x];  // 128 float4 = 512 floats
}

// ---------------------------------------------------------------- compose z-GEMM (one step, both dirs)
__global__ __launch_bounds__(256)
void k_compose_z(const float* __restrict__ e,
                 const float* __restrict__ hF, const float* __restrict__ hB,
                 const float* __restrict__ Wih_f, const float* __restrict__ Whh_f,
                 const float* __restrict__ bih_f, const float* __restrict__ bhh_f,
                 const float* __restrict__ Wih_b, const float* __restrict__ Whh_b,
                 const float* __restrict__ bih_b, const float* __restrict__ bhh_b,
                 float* __restrict__ zbuf, int stepk)
{
    __shared__ float As[16][64];
    __shared__ float Bs[16][64];
    const int d  = blockIdx.z;
    const int Mb = blockIdx.y * 64;
    const int Nb = blockIdx.x * 64;
    const int t  = threadIdx.x;

    const float* Wih = d ? Wih_b : Wih_f;
    const float* Whh = d ? Whh_b : Whh_f;
    const float* bih = d ? bih_b : bih_f;
    const float* bhh = d ? bhh_b : bhh_f;
    const float* h   = d ? hB : hF;
    const int child  = d ? (7 - stepk) : stepk;

    const int ml = t & 63;
    const int ko = (t >> 6) * 4;
    const int m  = Mb + ml;
    const int g  = m >> 4, b = m & 15;
    const float* xrow = e + ((size_t)((g * 8 + child) * 16 + b)) * S_;
    const float* hrow = h + (size_t)m * S_;
    const int n  = Nb + ml;
    const float* wi = Wih + (size_t)n * S_;
    const float* wh = Whh + (size_t)n * S_;

    const int tx = t & 15, ty = t >> 4;
    float acc[4][4] = {};

    for (int kk = 0; kk < 1024; kk += 16) {
        const float* ar = (kk < 512) ? (xrow + kk + ko) : (hrow + kk - 512 + ko);
        const float* br = (kk < 512) ? (wi + kk + ko)   : (wh + kk - 512 + ko);
        float4 av = *(const float4*)ar;
        float4 bv = *(const float4*)br;
        __syncthreads();
        As[ko + 0][ml] = av.x; As[ko + 1][ml] = av.y; As[ko + 2][ml] = av.z; As[ko + 3][ml] = av.w;
        Bs[ko + 0][ml] = bv.x; Bs[ko + 1][ml] = bv.y; Bs[ko + 2][ml] = bv.z; Bs[ko + 3][ml] = bv.w;
        __syncthreads();
#pragma unroll
        for (int k = 0; k < 16; ++k) {
            float a[4], bb[4];
#pragma unroll
            for (int i = 0; i < 4; ++i) a[i]  = As[k][ty * 4 + i];
#pragma unroll
            for (int j = 0; j < 4; ++j) bb[j] = Bs[k][tx * 4 + j];
#pragma unroll
            for (int i = 0; i < 4; ++i)
#pragma unroll
                for (int j = 0; j < 4; ++j) acc[i][j] += a[i] * bb[j];
        }
    }
#pragma unroll
    for (int i = 0; i < 4; ++i) {
        int mm = Mb + ty * 4 + i;
#pragma unroll
        for (int j = 0; j < 4; ++j) {
            int nn = Nb + tx * 4 + j;
            zbuf[((size_t)(d * 512 + mm)) * S4_ + nn] = acc[i][j] + bih[nn] + bhh[nn];
        }
    }
}

// ---------------------------------------------------------------- compose gate update
__global__ __launch_bounds__(256)
void k_compose_gates(const float* __restrict__ zbuf,
                     float* __restrict__ hF, float* __restrict__ cF,
                     float* __restrict__ hB, float* __restrict__ cB)
{
    int idx = blockIdx.x * 256 + threadIdx.x;  // 2*512*512
    int d   = idx >> 18;
    int rem = idx & ((1 << 18) - 1);
    int gb  = rem >> 9;
    int u   = rem & 511;
    const float* z = zbuf + ((size_t)(d * 512 + gb)) * S4_;
    float zi = z[u], zf = z[u + 512], zg = z[u + 1024], zo = z[u + 1536];
    float* hptr = d ? hB : hF;
    float* cptr = d ? cB : cF;
    float c = cptr[gb * S_ + u];
    c = sigm(zf) * c + sigm(zi) * tanhf(zg);
    hptr[gb * S_ + u] = sigm(zo) * tanhf(c);
    cptr[gb * S_ + u] = c;
}

// ---------------------------------------------------------------- comp = tanh([hF|hB] @ Wc.T + bc)
__global__ __launch_bounds__(256)
void k_comp(const float* __restrict__ hF, const float* __restrict__ hB,
            const float* __restrict__ Wc, const float* __restrict__ bc,
            float* __restrict__ comp)
{
    __shared__ float As[16][64];
    __shared__ float Bs[16][64];
    const int Mb = blockIdx.y * 64;
    const int Nb = blockIdx.x * 64;
    const int t  = threadIdx.x;
    const int ml = t & 63;
    const int ko = (t >> 6) * 4;
    const int m  = Mb + ml;
    const float* fr = hF + (size_t)m * S_;
    const float* br_ = hB + (size_t)m * S_;
    const int n  = Nb + ml;
    const float* wr = Wc + (size_t)n * 1024;
    const int tx = t & 15, ty = t >> 4;
    float acc[4][4] = {};

    for (int kk = 0; kk < 1024; kk += 16) {
        const float* ar = (kk < 512) ? (fr + kk + ko) : (br_ + kk - 512 + ko);
        float4 av = *(const float4*)ar;
        float4 bv = *(const float4*)(wr + kk + ko);
        __syncthreads();
        As[ko + 0][ml] = av.x; As[ko + 1][ml] = av.y; As[ko + 2][ml] = av.z; As[ko + 3][ml] = av.w;
        Bs[ko + 0][ml] = bv.x; Bs[ko + 1][ml] = bv.y; Bs[ko + 2][ml] = bv.z; Bs[ko + 3][ml] = bv.w;
        __syncthreads();
#pragma unroll
        for (int k = 0; k < 16; ++k) {
            float a[4], bb[4];
#pragma unroll
            for (int i = 0; i < 4; ++i) a[i]  = As[k][ty * 4 + i];
#pragma unroll
            for (int j = 0; j < 4; ++j) bb[j] = Bs[k][tx * 4 + j];
#pragma unroll
            for (int i = 0; i < 4; ++i)
#pragma unroll
                for (int j = 0; j < 4; ++j) acc[i][j] += a[i] * bb[j];
        }
    }
#pragma unroll
    for (int i = 0; i < 4; ++i) {
        int mm = Mb + ty * 4 + i;
#pragma unroll
        for (int j = 0; j < 4; ++j) {
            int nn = Nb + tx * 4 + j;
            comp[(size_t)mm * S_ + nn] = tanhf(acc[i][j] + bc[nn]);
        }
    }
}

// ---------------------------------------------------------------- zxt = x_step @ Wih_s.T + bih_s + bhh_s
// Output TRANSPOSED for the scan: zxt[((s*64 + blk)*4 + g)*128 + b*8 + ui]
__global__ __launch_bounds__(256)
void k_zx(const int* __restrict__ tokens, const float* __restrict__ emb,
          const float* __restrict__ e, const float* __restrict__ comp,
          const float* __restrict__ Wih, const float* __restrict__ bih,
          const float* __restrict__ bhh, float* __restrict__ zxt)
{
    __shared__ float As[16][64];
    __shared__ float Bs[16][64];
    const int Mb = blockIdx.y * 64;
    const int Nb = blockIdx.x * 64;
    const int t  = threadIdx.x;
    const int ml = t & 63;
    const int ko = (t >> 6) * 4;

    int m = Mb + ml;
    int s = m >> 4; if (s > 320) s = 320;
    int b = m & 15;
    const float* xrow;
    if (s == 0) xrow = emb + (size_t)tokens[0] * S_;
    else {
        int j = s - 1, g = j / 10, r = j - g * 10;
        if (r == 0)      xrow = emb + (size_t)tokens[0] * S_;
        else if (r <= 8) xrow = e + ((size_t)((g * 8 + r - 1) * 16 + b)) * S_;
        else             xrow = comp + ((size_t)(g * 16 + b)) * S_;
    }
    const int n = Nb + ml;
    const float* wr = Wih + (size_t)n * S_;
    const int tx = t & 15, ty = t >> 4;
    float acc[4][4] = {};

    for (int kk = 0; kk < 512; kk += 16) {
        float4 av = *(const float4*)(xrow + kk + ko);
        float4 bv = *(const float4*)(wr + kk + ko);
        __syncthreads();
        As[ko + 0][ml] = av.x; As[ko + 1][ml] = av.y; As[ko + 2][ml] = av.z; As[ko + 3][ml] = av.w;
        Bs[ko + 0][ml] = bv.x; Bs[ko + 1][ml] = bv.y; Bs[ko + 2][ml] = bv.z; Bs[ko + 3][ml] = bv.w;
        __syncthreads();
#pragma unroll
        for (int k = 0; k < 16; ++k) {
            float a[4], bb[4];
#pragma unroll
            for (int i = 0; i < 4; ++i) a[i]  = As[k][ty * 4 + i];
#pragma unroll
            for (int j = 0; j < 4; ++j) bb[j] = Bs[k][tx * 4 + j];
#pragma unroll
            for (int i = 0; i < 4; ++i)
#pragma unroll
                for (int j = 0; j < 4; ++j) acc[i][j] += a[i] * bb[j];
        }
    }
#pragma unroll
    for (int i = 0; i < 4; ++i) {
        int mm = Mb + ty * 4 + i;
        int ss = mm >> 4, bb2 = mm & 15;
#pragma unroll
        for (int j = 0; j < 4; ++j) {
            int nn = Nb + tx * 4 + j;
            int g = nn >> 9, un = nn & 511;
            zxt[(((size_t)ss * 64 + (un >> 3)) * 4 + g) * 128 + bb2 * 8 + (un & 7)]
                = acc[i][j] + bih[nn] + bhh[nn];
        }
    }
}

// ---------------------------------------------------------------- persistent stack-LSTM scan (r5 structure)
__global__ __launch_bounds__(256)
void k_scan(const float* __restrict__ zxt, const float* __restrict__ Whh,
            float* __restrict__ hseq,      // [(NSTEPS+1)][16][512]; hseq[0] zeroed
            float* __restrict__ hp, int* __restrict__ cnt)  // cnt zeroed
{
    __shared__ float4 wlin[8 * 513];
    __shared__ float4 hlin[8 * 257];
    __shared__ float  zred[8][32 * 17];
    const int t  = threadIdx.x;
    const int u0 = (int)blockIdx.x * 8;

#pragma unroll 4
    for (int q = 0; q < 16; ++q) {
        int v  = t * 16 + q;
        int kc = v >> 9, r = v & 511;
        int k4 = r >> 5, rr = r & 31;
        int j  = rr >> 3, nq = rr & 7;
        int lr = nq * 4 + j;
        int n  = (lr >> 3) * 512 + u0 + (lr & 7);
        int k  = kc * 64 + k4 * 4;
        wlin[kc * 513 + r] = *(const float4*)(Whh + (size_t)n * S_ + k);
    }

    const int kc = t >> 5;
    const int pt = t & 31;
    const int bq = pt >> 3;
    const int nq = pt & 7;
    const int hbase = kc * 257 + bq;
    const int wbase = kc * 513 + nq;

    const int gb_b  = t >> 3;
    const int gb_ui = t & 7;
    float creg = 0.0f;

    for (int s = 0; s < NSTEPS_; ++s) {
        float zxr[4];
        if (t < 128) {
            const float* zp = zxt + (((size_t)s * 64 + blockIdx.x) * 4) * 128 + t;
#pragma unroll
            for (int g = 0; g < 4; ++g) zxr[g] = zp[g * 128];
        }
        if (s > 0) {
            if (t == 0) {
                while (__hip_atomic_load(&cnt[s - 1], __ATOMIC_RELAXED,
                                         __HIP_MEMORY_SCOPE_AGENT) < SCAN_NB) { }
            }
            __syncthreads();
        }
        {
            int b = t >> 4;
            int kbase = (t & 15) * 32;
            const float4* src = (const float4*)(hseq + (size_t)s * 8192 + b * S_ + kbase);
#pragma unroll
            for (int q = 0; q < 8; ++q) {
                int k = kbase + q * 4;
                hlin[(k >> 6) * 257 + ((k & 63) >> 2) * 16 + (b >> 2) + (b & 3) * 4] = src[q];
            }
        }
        __syncthreads();
        float acc[4][4] = {{0.f,0.f,0.f,0.f},{0.f,0.f,0.f,0.f},{0.f,0.f,0.f,0.f},{0.f,0.f,0.f,0.f}};
#pragma unroll
        for (int k4 = 0; k4 < 16; ++k4) {
            float4 hv[4], wv[4];
#pragma unroll
            for (int i = 0; i < 4; ++i) hv[i] = hlin[hbase + k4 * 16 + i * 4];
#pragma unroll
            for (int j = 0; j < 4; ++j) wv[j] = wlin[wbase + k4 * 32 + j * 8];
#pragma unroll
            for (int i = 0; i < 4; ++i)
#pragma unroll
                for (int j = 0; j < 4; ++j)
                    acc[i][j] += hv[i].x * wv[j].x + hv[i].y * wv[j].y
                               + hv[i].z * wv[j].z + hv[i].w * wv[j].w;
        }
#pragma unroll
        for (int i = 0; i < 4; ++i)
#pragma unroll
            for (int j = 0; j < 4; ++j)
                zred[kc][pt * 17 + i * 4 + j] = acc[i][j];
        __syncthreads();
        if (t < 128) {
            float z[4];
#pragma unroll
            for (int g = 0; g < 4; ++g) {
                int lr  = g * 8 + gb_ui;
                int idx = ((gb_b >> 2) * 8 + (lr >> 2)) * 17 + (gb_b & 3) * 4 + (lr & 3);
                float sum = zred[0][idx];
#pragma unroll
                for (int c = 1; c < 8; ++c) sum += zred[c][idx];
                z[g] = zxr[g] + sum;
            }
            creg = sigm(z[1]) * creg + sigm(z[0]) * tanhf(z[2]);
            float hh = sigm(z[3]) * tanhf(creg);
            __hip_atomic_store(&hseq[(size_t)(s + 1) * 8192 + gb_b * S_ + u0 + gb_ui], hh,
                               __ATOMIC_RELAXED, __HIP_MEMORY_SCOPE_AGENT);
            if (s >= 1) {
                int j2 = s - 1, g2 = j2 / 10, r = j2 - g2 * 10;
                if (r <= 7)
                    hp[((size_t)((g2 * 8 + r) * 16 + gb_b)) * S_ + u0 + gb_ui] = hh;
            }
        }
        asm volatile("s_waitcnt vmcnt(0)" ::: "memory");
        __syncthreads();
        if (t == 0)
            __hip_atomic_fetch_add(&cnt[s], 1, __ATOMIC_RELAXED,
                                   __HIP_MEMORY_SCOPE_AGENT);
    }
}

// ---------------------------------------------------------------- legacy per-step stack kernel (ws fallback)
__global__ __launch_bounds__(256)
void k_stack_step(const float* __restrict__ e, const float* __restrict__ comp,
                  const int* __restrict__ tokens, const float* __restrict__ emb,
                  const float* __restrict__ Wih, const float* __restrict__ Whh,
                  const float* __restrict__ bih, const float* __restrict__ bhh,
                  const float* __restrict__ hsrc, float* __restrict__ hdst,
                  float* __restrict__ cst, float* __restrict__ hp, int step)
{
    __shared__ float zsh[128];
    const int t    = threadIdx.x;
    const int p    = t >> 1, half = t & 1;
    const int b    = p >> 3, rest = p & 7;
    const int ul   = rest >> 2, gate = rest & 3;
    const int unit = blockIdx.x * 2 + ul;
    const int n    = gate * 512 + unit;

    const float* row;
    if (half == 0) {
        const float* xs;
        if (step == 0) xs = emb + (size_t)tokens[0] * S_;
        else {
            int j = step - 1, g = j / 10, r = j - g * 10;
            if (r == 0)      xs = emb + (size_t)tokens[0] * S_;
            else if (r <= 8) xs = e + ((size_t)((g * 8 + r - 1) * 16 + b)) * S_;
            else             xs = comp + ((size_t)(g * 16 + b)) * S_;
        }
        row = xs;
    } else {
        row = hsrc + (size_t)b * S_;
    }
    const float* w = (half == 0 ? Wih : Whh) + (size_t)n * S_;

    const float4* r4 = (const float4*)row;
    const float4* w4 = (const float4*)w;
    float ax = 0.f, ay = 0.f, az = 0.f, aw = 0.f;
#pragma unroll 8
    for (int q = 0; q < 128; ++q) {
        float4 a = r4[q], ww = w4[q];
        ax += a.x * ww.x; ay += a.y * ww.y; az += a.z * ww.z; aw += a.w * ww.w;
    }
    float s = (ax + ay) + (az + aw);
    float o = __shfl_xor(s, 1);
    if (half == 0) zsh[p] = s + o + bih[n] + bhh[n];
    __syncthreads();

    if (t < 32) {
        int b2   = t >> 1;
        int u2   = blockIdx.x * 2 + (t & 1);
        int base = b2 * 8 + (t & 1) * 4;
        float zi = zsh[base + 0], zf = zsh[base + 1], zg = zsh[base + 2], zo = zsh[base + 3];
        float c  = cst[b2 * S_ + u2];
        c = sigm(zf) * c + sigm(zi) * tanhf(zg);
        float hh = sigm(zo) * tanhf(c);
        cst[b2 * S_ + u2]  = c;
        hdst[b2 * S_ + u2] = hh;
        if (step >= 1) {
            int j = step - 1, g = j / 10, r = j - g * 10;
            if (r <= 7) {
                int tt = g * 8 + r;
                hp[((size_t)(tt * 16 + b2)) * S_ + u2] = hh;
            }
        }
    }
}

// ---------------------------------------------------------------- token logit (one wave per row; exact fp32)
__global__ __launch_bounds__(64)
void k_tok(const int* __restrict__ tokens, const float* __restrict__ hp,
           const float* __restrict__ Wout, const float* __restrict__ bout,
           float* __restrict__ tl)
{
    int row  = blockIdx.x;
    int lane = threadIdx.x;
    int tok  = tokens[row];
    const float4* a = (const float4*)(hp + (size_t)row * S_);
    const float4* w = (const float4*)(Wout + (size_t)tok * S_);
    float s = 0.f;
    for (int q = lane; q < 128; q += 64) {
        float4 av = a[q], wv = w[q];
        s += av.x * wv.x + av.y * wv.y + av.z * wv.z + av.w * wv.w;
    }
    for (int off = 32; off; off >>= 1) s += __shfl_down(s, off);
    if (lane == 0) tl[row] = s + bout[tok];
}

// ---------------------------------------------------------------- fp32 -> bf16 conversion (8 elems/thread)
__global__ __launch_bounds__(256)
void k_cvt(const float* __restrict__ src, unsigned short* __restrict__ dst, int n)
{
    int i = (blockIdx.x * 256 + threadIdx.x) * 8;
    if (i >= n) return;
    float4 a = *(const float4*)(src + i);
    float4 b = *(const float4*)(src + i + 4);
    union { unsigned short u[8]; uint4 v; } r;
    r.u[0] = f2bf(a.x); r.u[1] = f2bf(a.y); r.u[2] = f2bf(a.z); r.u[3] = f2bf(a.w);
    r.u[4] = f2bf(b.x); r.u[5] = f2bf(b.y); r.u[6] = f2bf(b.z); r.u[7] = f2bf(b.w);
    *(uint4*)(dst + i) = r.v;
}

// ---------------------------------------------------------------- MFMA logits GEMM + online LSE partials
// M=4096, N=32000, K=512 bf16 inputs, fp32 accum. 128x128 tile, 4 waves,
// 4x4 fragments of mfma_f32_16x16x32_bf16 per wave, frags direct-from-global
// (hpb ~4MB LLC-resident; woutb 32MB streamed once, then LLC). Grid (32,250):
// M-tile fastest so co-scheduled blocks share the B-panel in L2.
// C/D layout: col=lane&15, row=(lane>>4)*4+reg [HW-verified]. A/B k-mapping:
// lane supplies 8 contiguous k at k0=(lane>>4)*8 (any common k-permutation
// cancels between A and B, so only the row/col lane mapping matters).
__global__ __launch_bounds__(256)
void k_lse_mfma(const unsigned short* __restrict__ hpb,
                const unsigned short* __restrict__ woutb,
                const float* __restrict__ bout, float* __restrict__ pmax,
                float* __restrict__ psum)
{
    __shared__ float maxsh[128][2];
    __shared__ float sumsh[128][2];
    __shared__ float mrow_sh[128];
    const int t  = threadIdx.x;
    const int w  = t >> 6, l = t & 63;
    const int wm = w & 1, wn = w >> 1;
    const int lr = l & 15, lg = l >> 4;
    const int Mb = blockIdx.x * 128;
    const int Nb = blockIdx.y * 128;

    f32x4 acc[4][4] = {};
    const unsigned short* arow[4];
    const unsigned short* brow[4];
#pragma unroll
    for (int i = 0; i < 4; ++i)
        arow[i] = hpb + (size_t)(Mb + wm * 64 + i * 16 + lr) * 512 + lg * 8;
#pragma unroll
    for (int j = 0; j < 4; ++j)
        brow[j] = woutb + (size_t)(Nb + wn * 64 + j * 16 + lr) * 512 + lg * 8;

    for (int kt = 0; kt < 16; ++kt) {
        bf16x8 af[4], bf[4];
#pragma unroll
        for (int i = 0; i < 4; ++i) af[i] = *(const bf16x8*)(arow[i] + kt * 32);
#pragma unroll
        for (int j = 0; j < 4; ++j) bf[j] = *(const bf16x8*)(brow[j] + kt * 32);
#pragma unroll
        for (int i = 0; i < 4; ++i)
#pragma unroll
            for (int j = 0; j < 4; ++j)
                acc[i][j] = __builtin_amdgcn_mfma_f32_16x16x32_bf16(af[i], bf[j], acc[i][j], 0, 0, 0);
    }

    float bv[4];
#pragma unroll
    for (int j = 0; j < 4; ++j) bv[j] = bout[Nb + wn * 64 + j * 16 + lr];

    // phase 1: per-row max (row = wm*64 + mi*16 + lg*4 + reg; butterfly over lr)
    float rmax[4][4];
#pragma unroll
    for (int mi = 0; mi < 4; ++mi)
#pragma unroll
        for (int r = 0; r < 4; ++r) {
            float m = -INFINITY;
#pragma unroll
            for (int j = 0; j < 4; ++j) m = fmaxf(m, acc[mi][j][r] + bv[j]);
            m = fmaxf(m, __shfl_xor(m, 1));
            m = fmaxf(m, __shfl_xor(m, 2));
            m = fmaxf(m, __shfl_xor(m, 4));
            m = fmaxf(m, __shfl_xor(m, 8));
            rmax[mi][r] = m;
        }
    if (lr == 0) {
#pragma unroll
        for (int mi = 0; mi < 4; ++mi)
#pragma unroll
            for (int r = 0; r < 4; ++r)
                maxsh[wm * 64 + mi * 16 + lg * 4 + r][wn] = rmax[mi][r];
    }
    __syncthreads();
    if (t < 128) mrow_sh[t] = fmaxf(maxsh[t][0], maxsh[t][1]);
    __syncthreads();
    // phase 2: per-row sum of exp at the combined max
#pragma unroll
    for (int mi = 0; mi < 4; ++mi)
#pragma unroll
        for (int r = 0; r < 4; ++r) {
            float M = mrow_sh[wm * 64 + mi * 16 + lg * 4 + r];
            float s = 0.f;
#pragma unroll
            for (int j = 0; j < 4; ++j) s += expf(acc[mi][j][r] + bv[j] - M);
            s += __shfl_xor(s, 1);
            s += __shfl_xor(s, 2);
            s += __shfl_xor(s, 4);
            s += __shfl_xor(s, 8);
            if (lr == 0) sumsh[wm * 64 + mi * 16 + lg * 4 + r][wn] = s;
        }
    __syncthreads();
    if (t < 128) {
        size_t off = (size_t)(Mb + t) * NT_LSE_ + blockIdx.y;
        pmax[off] = mrow_sh[t];
        psum[off] = sumsh[t][0] + sumsh[t][1];
    }
}

// ---------------------------------------------------------------- fp32 logits GEMM + LSE (legacy fallback)
__global__ __launch_bounds__(256)
void k_lse(const float* __restrict__ hp, const float* __restrict__ Wout,
           const float* __restrict__ bout, float* __restrict__ pmax,
           float* __restrict__ psum)
{
    __shared__ float As[16][128];
    __shared__ float Bs[16][128];
    __shared__ float red[128][17];
    __shared__ float rmax[128];
    const int Nb = blockIdx.x * 128;
    const int Mb = blockIdx.y * 128;
    const int t  = threadIdx.x;
    const int ml = t & 127, ko = (t >> 7) * 8;
    const float* arow = hp   + (size_t)(Mb + ml) * S_;
    const float* brow = Wout + (size_t)(Nb + ml) * S_;
    const int tx = t & 15, ty = t >> 4;
    float acc[8][8] = {};

    for (int kk = 0; kk < 512; kk += 16) {
        float4 a0 = *(const float4*)(arow + kk + ko);
        float4 a1 = *(const float4*)(arow + kk + ko + 4);
        float4 b0 = *(const float4*)(brow + kk + ko);
        float4 b1 = *(const float4*)(brow + kk + ko + 4);
        __syncthreads();
        As[ko + 0][ml] = a0.x; As[ko + 1][ml] = a0.y; As[ko + 2][ml] = a0.z; As[ko + 3][ml] = a0.w;
        As[ko + 4][ml] = a1.x; As[ko + 5][ml] = a1.y; As[ko + 6][ml] = a1.z; As[ko + 7][ml] = a1.w;
        Bs[ko + 0][ml] = b0.x; Bs[ko + 1][ml] = b0.y; Bs[ko + 2][ml] = b0.z; Bs[ko + 3][ml] = b0.w;
        Bs[ko + 4][ml] = b1.x; Bs[ko + 5][ml] = b1.y; Bs[ko + 6][ml] = b1.z; Bs[ko + 7][ml] = b1.w;
        __syncthreads();
#pragma unroll
        for (int k = 0; k < 16; ++k) {
            float a[8], bb[8];
#pragma unroll
            for (int i = 0; i < 8; ++i) a[i]  = As[k][ty * 8 + i];
#pragma unroll
            for (int j = 0; j < 8; ++j) bb[j] = Bs[k][tx * 8 + j];
#pragma unroll
            for (int i = 0; i < 8; ++i)
#pragma unroll
                for (int j = 0; j < 8; ++j) acc[i][j] += a[i] * bb[j];
        }
    }

    float bv[8];
#pragma unroll
    for (int j = 0; j < 8; ++j) bv[j] = bout[Nb + tx * 8 + j];

#pragma unroll
    for (int i = 0; i < 8; ++i) {
        float m = -INFINITY;
#pragma unroll
        for (int j = 0; j < 8; ++j) m = fmaxf(m, acc[i][j] + bv[j]);
        red[ty * 8 + i][tx] = m;
    }
    __syncthreads();
    if (t < 128) {
        float m = red[t][0];
#pragma unroll
        for (int x = 1; x < 16; ++x) m = fmaxf(m, red[t][x]);
        rmax[t] = m;
    }
    __syncthreads();
#pragma unroll
    for (int i = 0; i < 8; ++i) {
        float m = rmax[ty * 8 + i];
        float ss = 0.f;
#pragma unroll
        for (int j = 0; j < 8; ++j) ss += expf(acc[i][j] + bv[j] - m);
        red[ty * 8 + i][tx] = ss;
    }
    __syncthreads();
    if (t < 128) {
        float ss = 0.f;
#pragma unroll
        for (int x = 0; x < 16; ++x) ss += red[t][x];
        size_t off = (size_t)(Mb + t) * NT_LSE_ + blockIdx.x;
        pmax[off] = rmax[t];
        psum[off] = ss;
    }
}

// ---------------------------------------------------------------- final reduce: loss = LSE - tok_logit
__global__ __launch_bounds__(256)
void k_final(const float* __restrict__ pmax, const float* __restrict__ psum,
             const float* __restrict__ tl, float* __restrict__ loss)
{
    int r = blockIdx.x * 256 + threadIdx.x;  // 4096 rows
    const float* pm = pmax + (size_t)r * NT_LSE_;
    const float* ps = psum + (size_t)r * NT_LSE_;
    float M = -INFINITY, Ssum = 0.f;
    for (int nt = 0; nt < NT_LSE_; ++nt) {
        float m2 = pm[nt], s2 = ps[nt];
        float nm = fmaxf(M, m2);
        Ssum = Ssum * expf(M - nm) + s2 * expf(m2 - nm);
        M = nm;
    }
    loss[r] = M + logf(Ssum) - tl[r];
}

// ================================================================ host launcher
extern "C" void kernel_launch(void* const* d_in, const int* in_sizes, int n_in,
                              void* d_out, int out_size, void* d_ws, size_t ws_size,
                              hipStream_t stream)
{
    const int*   tokens = (const int*)d_in[0];
    const float* emb    = (const float*)d_in[1];
    const float* Wih_s  = (const float*)d_in[2];
    const float* Whh_s  = (const float*)d_in[3];
    const float* bih_s  = (const float*)d_in[4];
    const float* bhh_s  = (const float*)d_in[5];
    const float* Wih_f  = (const float*)d_in[6];
    const float* Whh_f  = (const float*)d_in[7];
    const float* bih_f  = (const float*)d_in[8];
    const float* bhh_f  = (const float*)d_in[9];
    const float* Wih_b  = (const float*)d_in[10];
    const float* Whh_b  = (const float*)d_in[11];
    const float* bih_b  = (const float*)d_in[12];
    const float* bhh_b  = (const float*)d_in[13];
    const float* Wc     = (const float*)d_in[14];
    const float* bc     = (const float*)d_in[15];
    const float* Wout   = (const float*)d_in[16];
    const float* bout   = (const float*)d_in[17];
    float* loss = (float*)d_out;

    float* ws = (float*)d_ws;

    // ---- persistent-path layout (identical footprint to round 5)
    size_t off = 0;
    float* e    = ws + off; off += (size_t)T_ * B_ * S_;
    float* hF   = ws + off; off += (size_t)GB_ * S_;       // zero region start
    float* cF   = ws + off; off += (size_t)GB_ * S_;
    float* hB   = ws + off; off += (size_t)GB_ * S_;
    float* cB   = ws + off; off += (size_t)GB_ * S_;
    int*   cnt  = (int*)(ws + off); off += 512;            // NSTEPS counters (zeroed)
    float* hseq = ws + off; off += (size_t)(NSTEPS_ + 1) * B_ * S_;  // hseq[0] zeroed
    size_t zero_end = (size_t)T_ * B_ * S_ + 4 * (size_t)GB_ * S_ + 512 + (size_t)B_ * S_;
    float* zbuf = ws + off; off += (size_t)2 * GB_ * S4_;
    float* comp = ws + off; off += (size_t)GB_ * S_;
    float* hp   = ws + off; off += (size_t)T_ * B_ * S_;
    float* pmax = ws + off; off += (size_t)T_ * B_ * NT_LSE_;
    float* psum = ws + off; off += (size_t)T_ * B_ * NT_LSE_;
    float* tl   = ws + off; off += (size_t)T_ * B_;
    float* zxt  = ws + off; off += (size_t)MZX_ * S4_;
    size_t need_bytes = off * sizeof(float);

    // bf16 buffers overlay dead regions (no extra ws):
    //   hpb  (4096*512 bf16 = 4MB)   -> zbuf (8MB, dead after compose)
    //   woutb(32000*512 bf16 = 32MB) -> zxt  (42.5MB, dead after scan)
    unsigned short* hpb   = (unsigned short*)zbuf;
    unsigned short* woutb = (unsigned short*)zxt;

    if (ws_size >= need_bytes) {
        size_t zs = (size_t)T_ * B_ * S_;
        hipMemsetAsync(hF, 0, (zero_end - zs) * sizeof(float), stream);

        k_gather<<<T_ * B_, 128, 0, stream>>>(tokens, emb, e);
        for (int k = 0; k < 8; ++k) {
            k_compose_z<<<dim3(32, 8, 2), 256, 0, stream>>>(
                e, hF, hB, Wih_f, Whh_f, bih_f, bhh_f,
                Wih_b, Whh_b, bih_b, bhh_b, zbuf, k);
            k_compose_gates<<<2048, 256, 0, stream>>>(zbuf, hF, cF, hB, cB);
        }
        k_comp<<<dim3(8, 8), 256, 0, stream>>>(hF, hB, Wc, bc, comp);
        k_zx<<<dim3(32, 81), 256, 0, stream>>>(tokens, emb, e, comp,
                                               Wih_s, bih_s, bhh_s, zxt);
        k_scan<<<SCAN_NB, 256, 0, stream>>>(zxt, Whh_s, hseq, hp, cnt);

        // conversions AFTER scan (overlay targets dead by then)
        k_cvt<<<(T_ * B_ * S_) / (256 * 8), 256, 0, stream>>>(hp, hpb, T_ * B_ * S_);
        k_cvt<<<(V_ * S_) / (256 * 8), 256, 0, stream>>>(Wout, woutb, V_ * S_);

        k_tok<<<T_ * B_, 64, 0, stream>>>(tokens, hp, Wout, bout, tl);
        k_lse_mfma<<<dim3(32, NT_LSE_), 256, 0, stream>>>(hpb, woutb, bout, pmax, psum);
        k_final<<<16, 256, 0, stream>>>(pmax, psum, tl, loss);
    } else {
        // ---- legacy fallback layout (proven fp32 path)
        off = 0;
        float* e2    = ws + off; off += (size_t)T_ * B_ * S_;
        float* hF2   = ws + off; off += (size_t)GB_ * S_;
        float* cF2   = ws + off; off += (size_t)GB_ * S_;
        float* hB2   = ws + off; off += (size_t)GB_ * S_;
        float* cB2   = ws + off; off += (size_t)GB_ * S_;
        float* hs0   = ws + off; off += (size_t)B_ * S_;
        float* hs1   = ws + off; off += (size_t)B_ * S_;
        float* cs    = ws + off; off += (size_t)B_ * S_;
        float* zbuf2 = ws + off; off += (size_t)2 * GB_ * S4_;
        float* comp2 = ws + off; off += (size_t)GB_ * S_;
        float* hp2   = ws + off; off += (size_t)T_ * B_ * S_;
        float* pmax2 = ws + off; off += (size_t)T_ * B_ * NT_LSE_;
        float* psum2 = ws + off; off += (size_t)T_ * B_ * NT_LSE_;
        float* tl2   = ws + off; off += (size_t)T_ * B_;

        size_t zero_bytes = ((size_t)4 * GB_ * S_ + (size_t)3 * B_ * S_) * sizeof(float);
        hipMemsetAsync(hF2, 0, zero_bytes, stream);

        k_gather<<<T_ * B_, 128, 0, stream>>>(tokens, emb, e2);
        for (int k = 0; k < 8; ++k) {
            k_compose_z<<<dim3(32, 8, 2), 256, 0, stream>>>(
                e2, hF2, hB2, Wih_f, Whh_f, bih_f, bhh_f,
                Wih_b, Whh_b, bih_b, bhh_b, zbuf2, k);
            k_compose_gates<<<2048, 256, 0, stream>>>(zbuf2, hF2, cF2, hB2, cB2);
        }
        k_comp<<<dim3(8, 8), 256, 0, stream>>>(hF2, hB2, Wc, bc, comp2);

        float* hb[2] = { hs0, hs1 };
        for (int i = 0; i < NSTEPS_; ++i) {
            k_stack_step<<<256, 256, 0, stream>>>(e2, comp2, tokens, emb,
                                                  Wih_s, Whh_s, bih_s, bhh_s,
                                                  hb[i & 1], hb[(i + 1) & 1], cs, hp2, i);
        }
        k_tok<<<T_ * B_, 64, 0, stream>>>(tokens, hp2, Wout, bout, tl2);
        k_lse<<<dim3(NT_LSE_, 32), 256, 0, stream>>>(hp2, Wout, bout, pmax2, psum2);
        k_final<<<16, 256, 0, stream>>>(pmax2, psum2, tl2, loss);
    }
}